// Round 4
// baseline (771.037 us; speedup 1.0000x reference)
//
#include <hip/hip_runtime.h>
#include <hip/hip_bf16.h>
#include <hip/hip_fp16.h>
#include <cstdint>
#include <cstddef>
#include <cstring>

using bf16 = __hip_bfloat16;

constexpr int TS    = 1024;
constexpr int DIM   = 1024;
constexpr int MEMN  = 1024;
constexpr int CMEMN = 256;
constexpr int KVN   = 2304;   // CMEM + MEM + T
constexpr int TMEM  = 1280;   // MEM + CMEM

typedef __attribute__((ext_vector_type(8))) short short8;
typedef __attribute__((ext_vector_type(4))) float f32x4;

__device__ __forceinline__ unsigned short f2bf_us(float f){
    __hip_bfloat16 t = __float2bfloat16(f);
    unsigned short us; memcpy(&us, &t, 2); return us;
}
__device__ __forceinline__ int sw8(int row){ return (row & 7) ^ ((row >> 3) & 7); }

// XOR-swizzled LDS tile (rows of 64 shorts, swizzle on 8-short chunks)
__device__ __forceinline__ short8 ldfrag(const unsigned short* base, int row, int chunk) {
    int ch = chunk ^ sw8(row);
    return *(const short8*)(base + row*64 + ch*8);
}
__device__ __forceinline__ void gl2lds16(const void* g, void* l) {
    __builtin_amdgcn_global_load_lds(
        (const __attribute__((address_space(1))) void*)g,
        (__attribute__((address_space(3))) void*)l, 16, 0, 0);
}
__device__ __forceinline__ short8 ldg8(const unsigned short* p){ return *(const short8*)p; }

// ---------------- pack: fp32 -> bf16 staging ----------------
__global__ __launch_bounds__(256) void pack(
    const float* __restrict__ x, const float* __restrict__ memp,
    const float* __restrict__ cmem, const float* __restrict__ Wq,
    const float* __restrict__ Wkv, const float* __restrict__ Wout,
    const float* __restrict__ cw, const float* __restrict__ pe,
    unsigned short* __restrict__ kvin, unsigned short* __restrict__ wqb,
    unsigned short* __restrict__ wkvb, unsigned short* __restrict__ woutb,
    unsigned short* __restrict__ cw2b, unsigned short* __restrict__ peb)
{
    const size_t t8 = ((size_t)blockIdx.x * 256 + threadIdx.x) * 8;
    unsigned short h[8];
    if (t8 < 9437184) {
        size_t g = t8 >> 10;
        int cc = (int)(t8 & 1023);
        int b = (int)(g / KVN), j = (int)(g % KVN);
        const float* src;
        if (j < CMEMN)      src = cmem + ((size_t)b*CMEMN + j)*1024 + cc;
        else if (j < TMEM)  src = memp + ((size_t)b*MEMN + (j - CMEMN))*1024 + cc;
        else                src = x    + ((size_t)b*TS   + (j - TMEM))*1024 + cc;
        float4 f0 = *(const float4*)src; float4 f1 = *(const float4*)(src + 4);
        h[0]=f2bf_us(f0.x); h[1]=f2bf_us(f0.y); h[2]=f2bf_us(f0.z); h[3]=f2bf_us(f0.w);
        h[4]=f2bf_us(f1.x); h[5]=f2bf_us(f1.y); h[6]=f2bf_us(f1.z); h[7]=f2bf_us(f1.w);
        *(uint4*)(kvin + t8) = *(const uint4*)h;
    } else if (t8 < 13631488) {
        const float* src; unsigned short* dst; float sc = 1.0f;
        // Wq prescale: attn scale (1/8) x log2(e) so softmax can use exp2 directly
        if (t8 < 10485760)      { src = Wq   + (t8 - 9437184);  dst = wqb   + (t8 - 9437184); sc = 0.18033688011112043f; }
        else if (t8 < 12582912) { src = Wkv  + (t8 - 10485760); dst = wkvb  + (t8 - 10485760); }
        else                    { src = Wout + (t8 - 12582912); dst = woutb + (t8 - 12582912); }
        float4 f0 = *(const float4*)src; float4 f1 = *(const float4*)(src + 4);
        h[0]=f2bf_us(f0.x*sc); h[1]=f2bf_us(f0.y*sc); h[2]=f2bf_us(f0.z*sc); h[3]=f2bf_us(f0.w*sc);
        h[4]=f2bf_us(f1.x*sc); h[5]=f2bf_us(f1.y*sc); h[6]=f2bf_us(f1.z*sc); h[7]=f2bf_us(f1.w*sc);
        *(uint4*)dst = *(const uint4*)h;
    } else if (t8 < 17825792) {
        size_t o8 = t8 - 13631488;
        int o = (int)(o8 >> 12); int rem = (int)(o8 & 4095);
        int r = rem >> 10, i = rem & 1023;
        #pragma unroll
        for (int p = 0; p < 8; ++p) h[p] = f2bf_us(cw[(o << 12) + (i + p)*4 + r]);
        *(uint4*)(cw2b + o8) = *(const uint4*)h;
    } else {
        size_t o8 = t8 - 17825792;
        const float* src = pe + o8;
        float4 f0 = *(const float4*)src; float4 f1 = *(const float4*)(src + 4);
        h[0]=f2bf_us(f0.x); h[1]=f2bf_us(f0.y); h[2]=f2bf_us(f0.z); h[3]=f2bf_us(f0.w);
        h[4]=f2bf_us(f1.x); h[5]=f2bf_us(f1.y); h[6]=f2bf_us(f1.z); h[7]=f2bf_us(f1.w);
        *(uint4*)(peb + o8) = *(const uint4*)h;
    }
}

// ---------------- MFMA GEMM: C = A @ B^T (+bias) ----------------
template<int EPI, int QMODE>
__global__ __launch_bounds__(256) void gemm_mfma(
    const bf16* __restrict__ Abf, const bf16* __restrict__ Bbf,
    const float* __restrict__ bias, void* __restrict__ Cptr,
    void* __restrict__ C2, int M, int N, int K)
{
    __shared__ alignas(16) unsigned short As[128*64];
    __shared__ alignas(16) unsigned short Bs[128*64];
    const int tid = threadIdx.x, lane = tid & 63, w = tid >> 6;
    const int quad = lane >> 4, colq = lane & 15;
    const int wm = w >> 1, wn = w & 1;
    const int m0 = blockIdx.x * 128, n0 = blockIdx.y * 128;
    size_t abase;
    if (QMODE == 0)      abase = (size_t)m0 * K;
    else if (QMODE == 1) abase = ((size_t)((m0 >> 10)*KVN + TMEM + (m0 & 1023))) * 1024;
    else                 abase = ((size_t)((m0 >> 8)*KVN + CMEMN)) * 1024 + (size_t)(m0 & 255) * 4096;
    const unsigned short* Ag = (const unsigned short*)Abf + abase;
    const unsigned short* Bg = (const unsigned short*)Bbf + (size_t)n0 * K;

    const int srow0 = w*32 + (lane >> 3);
    const int sch2  = lane & 7;

    f32x4 acc[4][4];
    #pragma unroll
    for (int i = 0; i < 4; ++i)
        #pragma unroll
        for (int j = 0; j < 4; ++j) acc[i][j] = (f32x4){0.f,0.f,0.f,0.f};

    for (int k0 = 0; k0 < K; k0 += 64) {
        __syncthreads();
        #pragma unroll
        for (int c = 0; c < 4; ++c) {
            int rr = srow0 + c*8;
            int ch = sch2 ^ sw8(rr);
            gl2lds16(Ag + (size_t)rr*K + k0 + ch*8, &As[(w*32 + c*8)*64]);
            gl2lds16(Bg + (size_t)rr*K + k0 + ch*8, &Bs[(w*32 + c*8)*64]);
        }
        __syncthreads();
        short8 af[4][2], bfr[4][2];
        #pragma unroll
        for (int i = 0; i < 4; ++i) {
            af[i][0]  = ldfrag(As, wm*64 + i*16 + colq, quad);
            af[i][1]  = ldfrag(As, wm*64 + i*16 + colq, 4 + quad);
            bfr[i][0] = ldfrag(Bs, wn*64 + i*16 + colq, quad);
            bfr[i][1] = ldfrag(Bs, wn*64 + i*16 + colq, 4 + quad);
        }
        #pragma unroll
        for (int i = 0; i < 4; ++i)
            #pragma unroll
            for (int j = 0; j < 4; ++j) {
                f32x4 t = __builtin_amdgcn_mfma_f32_16x16x32_bf16(af[i][0], bfr[j][0], acc[i][j], 0, 0, 0);
                acc[i][j] = __builtin_amdgcn_mfma_f32_16x16x32_bf16(af[i][1], bfr[j][1], t, 0, 0, 0);
            }
    }
    if (EPI == 2) {
        const int b = m0 / KVN;
        const int jj0 = (m0 - b*KVN) + wm*64;
        if (n0 < 1024) {            // K half -> knat [b*KVN + j][1024]
            bf16* kn = (bf16*)Cptr;
            #pragma unroll
            for (int j = 0; j < 4; ++j) {
                int col = n0 + wn*64 + j*16 + colq;
                #pragma unroll
                for (int i = 0; i < 4; ++i)
                    #pragma unroll
                    for (int r = 0; r < 4; ++r)
                        kn[(size_t)(b*KVN + jj0 + i*16 + quad*4 + r)*1024 + col] =
                            __float2bfloat16(acc[i][j][r]);
            }
        } else {                    // V half -> Vh [((b*16+h)*64+d)*KVN + j]
            unsigned short* vp = (unsigned short*)C2;
            #pragma unroll
            for (int j = 0; j < 4; ++j) {
                int col = n0 + wn*64 + j*16 + colq;
                int hh = (col >> 6) & 15, d = col & 63;
                #pragma unroll
                for (int i = 0; i < 4; ++i) {
                    int jjb = jj0 + i*16 + quad*4;
                    ushort4 u;
                    u.x = f2bf_us(acc[i][j][0]); u.y = f2bf_us(acc[i][j][1]);
                    u.z = f2bf_us(acc[i][j][2]); u.w = f2bf_us(acc[i][j][3]);
                    *(ushort4*)(vp + ((size_t)((b*16 + hh)*64 + d))*KVN + jjb) = u;
                }
            }
        }
    } else {
        #pragma unroll
        for (int j = 0; j < 4; ++j) {
            int col = n0 + wn*64 + j*16 + colq;
            float bj = bias ? bias[col] : 0.0f;
            #pragma unroll
            for (int i = 0; i < 4; ++i)
                #pragma unroll
                for (int r = 0; r < 4; ++r) {
                    size_t row = (size_t)(m0 + wm*64 + i*16 + quad*4 + r);
                    float v = acc[i][j][r] + bj;
                    if (EPI == 1) ((bf16*)Cptr)[row*N + col] = __float2bfloat16(v);
                    else          ((float*)Cptr)[row*N + col] = v;
                }
        }
    }
}

// ---------------- Flash attention: 64-q-row blocks, PE direct-global ----------------
// Grid 1024 (b,h,q64), LPT order (heavy q0 first). 4 waves x 16 q-rows.
// LDS 40KB: K/V double-buffer (counted vmcnt, no drain in loop) + P slab.
// PE band B-fragments load directly from global (L2/L3-resident; per-lane rows
// of one fragment coalesce into full 128B lines). Band loads issue BEFORE the
// KV(t+2) stage so the compiler's pre-band-MFMA wait is a counted vmcnt that
// leaves the KV prefetch in flight. 3 blocks/CU target -> 12 waves/CU.
__global__ __launch_bounds__(256, 3) void attn(
    const unsigned short* __restrict__ qg,   // prescaled q bf16, [b*1024+i][1024]
    const unsigned short* __restrict__ kq,   // knat [b*KVN+j][1024]
    const unsigned short* __restrict__ vh,   // Vh [((b*16+h)*64+d)][KVN]
    const unsigned short* __restrict__ peb,  // [h][KVN][64] bf16
    bf16* __restrict__ out)                  // ao [b*1024+i][1024]
{
    __shared__ alignas(16) unsigned short Kt[2][64*64];  // 16 KB dbuf
    __shared__ alignas(16) unsigned short Vt[2][64*64];  // 16 KB dbuf, Vt[d][j]
    __shared__ alignas(16) unsigned short Pb[64*64];     //  8 KB per-wave P slabs

    const int tid  = threadIdx.x;
    const int lane = tid & 63, w = tid >> 6;
    const int quad = lane >> 4, colq = lane & 15;
    const int jr = lane >> 3, l7 = lane & 7;

    const int bx = blockIdx.x;
    const int b = bx & 3, h = (bx >> 2) & 15;
    const int q0 = (15 - (bx >> 6)) * 64;    // LPT: heavy blocks dispatched first
    const int i0 = q0 + 16*w;                // this wave's first q row

    const unsigned short* kbase = kq  + (size_t)b*KVN*1024 + h*64;
    const unsigned short* vbase = vh  + ((size_t)((b*16 + h)*64))*KVN;
    const unsigned short* pbase = peb + (size_t)h*KVN*64;

    // Q fragments direct from global (2 loads, oldest in vm queue)
    const unsigned short* qp = qg + ((size_t)(b*1024 + i0 + colq))*1024 + h*64;
    const short8 qa0 = ldg8(qp + quad*8);
    const short8 qa1 = ldg8(qp + 32 + quad*8);

    const int row0 = w*8 + jr;           // 0..31
    const int row1 = 32 + row0;          // 32..63
    const int ch0 = (l7 ^ sw8(row0))*8;
    const int ch1 = (l7 ^ sw8(row1))*8;

    auto stage_kv = [&](int kv0s, int buf) {
        gl2lds16(kbase + (size_t)(kv0s + row0)*1024 + ch0, &Kt[buf][(w*8)*64]);
        gl2lds16(kbase + (size_t)(kv0s + row1)*1024 + ch1, &Kt[buf][(32 + w*8)*64]);
        gl2lds16(vbase + (size_t)row0*KVN + kv0s + ch0, &Vt[buf][(w*8)*64]);
        gl2lds16(vbase + (size_t)row1*KVN + kv0s + ch1, &Vt[buf][(32 + w*8)*64]);
    };

    stage_kv(0, 0);
    stage_kv(64, 1);
    __builtin_amdgcn_sched_barrier(0);

    f32x4 oacc[4];
    float l_[4];
    #pragma unroll
    for (int dt = 0; dt < 4; ++dt) oacc[dt] = (f32x4){0.f,0.f,0.f,0.f};
    #pragma unroll
    for (int r = 0; r < 4; ++r) l_[r] = 0.f;
    const f32x4 zero4 = (f32x4){0.f,0.f,0.f,0.f};

    const int nkv = min(36, ((q0 + 63 + TMEM) >> 6) + 1);   // block-uniform bound
    int cur = 0;

    for (int kvt = 0; kvt < nkv; ++kvt) {
        const int kv0 = kvt * 64;
        // KV(t) landed for ALL waves after the barrier; KV(t+1) stays in flight
        asm volatile("s_waitcnt vmcnt(4)" ::: "memory");
        __builtin_amdgcn_s_barrier();

        const unsigned short* KtC = &Kt[cur][0];
        const unsigned short* VtC = &Vt[cur][0];
        short8 kf[4][2], vf[4][2];
        #pragma unroll
        for (int nt = 0; nt < 4; ++nt) {
            kf[nt][0] = ldfrag(KtC, nt*16 + colq, quad);
            kf[nt][1] = ldfrag(KtC, nt*16 + colq, 4 + quad);
            vf[nt][0] = ldfrag(VtC, nt*16 + colq, quad);
            vf[nt][1] = ldfrag(VtC, nt*16 + colq, 4 + quad);
        }
        // PE band fragments direct from global (issue early; hidden under
        // lgkm wait + barrier + QK MFMAs). Clamped rows feed masked cols only.
        const int cb = kv0 - i0 + 1008;
        short8 pf[5][2];
        #pragma unroll
        for (int pnt = 0; pnt < 5; ++pnt) {
            int cs = min(cb + pnt*16 + colq, KVN - 1);
            const unsigned short* pp = pbase + (size_t)cs*64;
            pf[pnt][0] = ldg8(pp + quad*8);
            pf[pnt][1] = ldg8(pp + 32 + quad*8);
        }
        asm volatile("s_waitcnt lgkmcnt(0)" ::: "memory");
        __builtin_amdgcn_s_barrier();        // all waves done reading buf[cur]

        // stage KV(t+2) into the freed buffer (AFTER band loads in the vm FIFO:
        // the compiler's band wait is then a counted vmcnt leaving these in flight)
        if (kvt + 2 < nkv) stage_kv(kv0 + 128, cur);
        __builtin_amdgcn_sched_barrier(0);

        // ---- MFMA phase: S = Q.K^T and pos band ----
        f32x4 facc[4], pacc[5];
        __builtin_amdgcn_s_setprio(1);
        #pragma unroll
        for (int nt = 0; nt < 4; ++nt) {
            f32x4 t = __builtin_amdgcn_mfma_f32_16x16x32_bf16(qa0, kf[nt][0], zero4, 0, 0, 0);
            facc[nt] = __builtin_amdgcn_mfma_f32_16x16x32_bf16(qa1, kf[nt][1], t, 0, 0, 0);
        }
        #pragma unroll
        for (int pnt = 0; pnt < 5; ++pnt) {
            f32x4 t = __builtin_amdgcn_mfma_f32_16x16x32_bf16(qa0, pf[pnt][0], zero4, 0, 0, 0);
            pacc[pnt] = __builtin_amdgcn_mfma_f32_16x16x32_bf16(qa1, pf[pnt][1], t, 0, 0, 0);
        }
        __builtin_amdgcn_s_setprio(0);

        // ---- softmax: gather + exp2 + P write (static-max, l deferred) ----
        const int prow0 = 16*w + 4*quad;
        #pragma unroll
        for (int r = 0; r < 4; ++r) {
            int tt = colq + 15 - 4*quad - r;
            int src = (lane & 48) | (tt & 15);
            float sh[5];
            #pragma unroll
            for (int p = 0; p < 5; ++p) sh[p] = __shfl(pacc[p][r], src, 64);
            int ig = i0 + 4*quad + r;
            float lsum = 0.f;
            float ps[4];
            #pragma unroll
            for (int nt = 0; nt < 4; ++nt) {
                float g = (tt < 16) ? sh[nt] : sh[nt + 1];
                float v = facc[nt][r] + g;
                int jg = kv0 + nt*16 + colq;
                float s = (jg - ig > TMEM) ? -1e30f : v;
                ps[nt] = __builtin_exp2f(s);   // log2e folded into q prescale
                lsum += ps[nt];
            }
            l_[r] += lsum;
            int prow = prow0 + r;
            int swp = sw8(prow);
            #pragma unroll
            for (int nt = 0; nt < 4; ++nt) {
                int cc = nt*16 + colq;
                Pb[prow*64 + (((cc >> 3) ^ swp))*8 + (cc & 7)] = f2bf_us(ps[nt]);
            }
        }
        // ---- PV (same-wave DS ordering: own writes visible to own reads) ----
        short8 pa0 = ldfrag(Pb, 16*w + colq, quad);
        short8 pa1 = ldfrag(Pb, 16*w + colq, 4 + quad);
        __builtin_amdgcn_s_setprio(1);
        #pragma unroll
        for (int dt = 0; dt < 4; ++dt) {
            f32x4 t = __builtin_amdgcn_mfma_f32_16x16x32_bf16(pa0, vf[dt][0], oacc[dt], 0, 0, 0);
            oacc[dt] = __builtin_amdgcn_mfma_f32_16x16x32_bf16(pa1, vf[dt][1], t, 0, 0, 0);
        }
        __builtin_amdgcn_s_setprio(0);
        cur ^= 1;
    }

    // ---- epilogue: reduce l across 16 colq lanes, normalize, store ----
    #pragma unroll
    for (int r = 0; r < 4; ++r) {
        float lt = l_[r];
        #pragma unroll
        for (int off = 1; off < 16; off <<= 1) lt += __shfl_xor(lt, off, 64);
        float inv = 1.0f / lt;
        size_t row = (size_t)(b*1024 + i0 + 4*quad + r);
        #pragma unroll
        for (int dt = 0; dt < 4; ++dt)
            out[row*1024 + h*64 + dt*16 + colq] = __float2bfloat16(oacc[dt][r] * inv);
    }
}

// new_mem = x (fp32 bit copy, 16 MB)
__global__ __launch_bounds__(256) void copy_u4(const uint4* __restrict__ src,
                                               uint4* __restrict__ dst, int n)
{
    int i = blockIdx.x * 256 + threadIdx.x;
    if (i < n) dst[i] = src[i];
}

extern "C" void kernel_launch(void* const* d_in, const int* in_sizes, int n_in,
                              void* d_out, int out_size, void* d_ws, size_t ws_size,
                              hipStream_t stream)
{
    const float* x    = (const float*)d_in[0];
    const float* memp = (const float*)d_in[1];
    const float* cmem = (const float*)d_in[2];
    const float* pe   = (const float*)d_in[3];
    const float* Wq   = (const float*)d_in[5];
    const float* Wkv  = (const float*)d_in[6];
    const float* Wout = (const float*)d_in[7];
    const float* bout = (const float*)d_in[8];
    const float* cw   = (const float*)d_in[9];
    const float* cb   = (const float*)d_in[10];
    float* outp = (float*)d_out;

    // ws layout (bytes), total ~94.9 MB
    char* wsb = (char*)d_ws;
    unsigned short* kvin  = (unsigned short*)(wsb);              // 18,874,368
    unsigned short* knat  = (unsigned short*)(wsb + 18874368);   // 18,874,368
    unsigned short* vhb   = (unsigned short*)(wsb + 37748736);   // 18,874,368
    unsigned short* qb    = (unsigned short*)(wsb + 56623104);   //  8,388,608
    bf16*           ao    = (bf16*)(wsb + 65011712);             //  8,388,608
    unsigned short* wqb   = (unsigned short*)(wsb + 73400320);   //  2,097,152
    unsigned short* wkvb  = (unsigned short*)(wsb + 75497472);   //  4,194,304
    unsigned short* woutb = (unsigned short*)(wsb + 79691776);   //  2,097,152
    unsigned short* cw2b  = (unsigned short*)(wsb + 81788928);   //  8,388,608
    unsigned short* peb   = (unsigned short*)(wsb + 90177536);   //  4,718,592

    // stage all bf16 operands (incl. prescaled Wq with log2e, bf16 pe)
    pack<<<dim3(9856), 256, 0, stream>>>(x, memp, cmem, Wq, Wkv, Wout, cw, pe,
        kvin, wqb, wkvb, woutb, cw2b, peb);
    // q = x @ (0.125*log2e*Wq)^T  (bf16, prescaled)
    gemm_mfma<1,1><<<dim3(32, 8), 256, 0, stream>>>((const bf16*)kvin, (const bf16*)wqb,
        nullptr, qb, nullptr, 4096, 1024, 1024);
    // kv = kvin @ Wkv^T -> K natural (knat), V transposed (vhb)
    gemm_mfma<2,0><<<dim3(72, 16), 256, 0, stream>>>((const bf16*)kvin, (const bf16*)wkvb,
        nullptr, knat, vhb, 9216, 2048, 1024);
    // flash attention -> ao  (1024 blocks: b, h, q/64; LPT order)
    attn<<<dim3(1024), 256, 0, stream>>>(qb, knat, vhb, peb, ao);
    // logits = ao @ Wout^T + bout -> d_out (fp32)
    gemm_mfma<0,0><<<dim3(32, 8), 256, 0, stream>>>(ao, (const bf16*)woutb,
        bout, outp, nullptr, 4096, 1024, 1024);
    // new_mem = x
    copy_u4<<<dim3(4096), 256, 0, stream>>>((const uint4*)x,
        (uint4*)(outp + 4194304), 1048576);
    // new_cmem = conv(mem) as GEMM (mem-region of kvin as 1024x4096)
    gemm_mfma<0,2><<<dim3(8, 8), 256, 0, stream>>>((const bf16*)kvin, (const bf16*)cw2b,
        cb, outp + 8388608, nullptr, 1024, 1024, 4096);
}

// Round 5
// 726.474 us; speedup vs baseline: 1.0613x; 1.0613x over previous
//
#include <hip/hip_runtime.h>
#include <hip/hip_bf16.h>
#include <hip/hip_fp16.h>
#include <cstdint>
#include <cstddef>
#include <cstring>

using bf16 = __hip_bfloat16;

constexpr int TS    = 1024;
constexpr int DIM   = 1024;
constexpr int MEMN  = 1024;
constexpr int CMEMN = 256;
constexpr int KVN   = 2304;   // CMEM + MEM + T
constexpr int TMEM  = 1280;   // MEM + CMEM

typedef __attribute__((ext_vector_type(8))) short short8;
typedef __attribute__((ext_vector_type(4))) float f32x4;

__device__ __forceinline__ unsigned short f2bf_us(float f){
    __hip_bfloat16 t = __float2bfloat16(f);
    unsigned short us; memcpy(&us, &t, 2); return us;
}
__device__ __forceinline__ int sw8(int row){ return (row & 7) ^ ((row >> 3) & 7); }

// XOR-swizzled LDS tile (rows of 64 shorts, swizzle on 8-short chunks)
__device__ __forceinline__ short8 ldfrag(const unsigned short* base, int row, int chunk) {
    int ch = chunk ^ sw8(row);
    return *(const short8*)(base + row*64 + ch*8);
}
__device__ __forceinline__ void gl2lds16(const void* g, void* l) {
    __builtin_amdgcn_global_load_lds(
        (const __attribute__((address_space(1))) void*)g,
        (__attribute__((address_space(3))) void*)l, 16, 0, 0);
}
__device__ __forceinline__ short8 ldg8(const unsigned short* p){ return *(const short8*)p; }

// ---------------- pack: fp32 -> bf16 staging ----------------
__global__ __launch_bounds__(256) void pack(
    const float* __restrict__ x, const float* __restrict__ memp,
    const float* __restrict__ cmem, const float* __restrict__ Wq,
    const float* __restrict__ Wkv, const float* __restrict__ Wout,
    const float* __restrict__ cw, const float* __restrict__ pe,
    unsigned short* __restrict__ kvin, unsigned short* __restrict__ wqb,
    unsigned short* __restrict__ wkvb, unsigned short* __restrict__ woutb,
    unsigned short* __restrict__ cw2b, unsigned short* __restrict__ peb)
{
    const size_t t8 = ((size_t)blockIdx.x * 256 + threadIdx.x) * 8;
    unsigned short h[8];
    if (t8 < 9437184) {
        size_t g = t8 >> 10;
        int cc = (int)(t8 & 1023);
        int b = (int)(g / KVN), j = (int)(g % KVN);
        const float* src;
        if (j < CMEMN)      src = cmem + ((size_t)b*CMEMN + j)*1024 + cc;
        else if (j < TMEM)  src = memp + ((size_t)b*MEMN + (j - CMEMN))*1024 + cc;
        else                src = x    + ((size_t)b*TS   + (j - TMEM))*1024 + cc;
        float4 f0 = *(const float4*)src; float4 f1 = *(const float4*)(src + 4);
        h[0]=f2bf_us(f0.x); h[1]=f2bf_us(f0.y); h[2]=f2bf_us(f0.z); h[3]=f2bf_us(f0.w);
        h[4]=f2bf_us(f1.x); h[5]=f2bf_us(f1.y); h[6]=f2bf_us(f1.z); h[7]=f2bf_us(f1.w);
        *(uint4*)(kvin + t8) = *(const uint4*)h;
    } else if (t8 < 13631488) {
        const float* src; unsigned short* dst; float sc = 1.0f;
        // Wq prescale: attn scale (1/8) x log2(e) so softmax can use exp2 directly
        if (t8 < 10485760)      { src = Wq   + (t8 - 9437184);  dst = wqb   + (t8 - 9437184); sc = 0.18033688011112043f; }
        else if (t8 < 12582912) { src = Wkv  + (t8 - 10485760); dst = wkvb  + (t8 - 10485760); }
        else                    { src = Wout + (t8 - 12582912); dst = woutb + (t8 - 12582912); }
        float4 f0 = *(const float4*)src; float4 f1 = *(const float4*)(src + 4);
        h[0]=f2bf_us(f0.x*sc); h[1]=f2bf_us(f0.y*sc); h[2]=f2bf_us(f0.z*sc); h[3]=f2bf_us(f0.w*sc);
        h[4]=f2bf_us(f1.x*sc); h[5]=f2bf_us(f1.y*sc); h[6]=f2bf_us(f1.z*sc); h[7]=f2bf_us(f1.w*sc);
        *(uint4*)dst = *(const uint4*)h;
    } else if (t8 < 17825792) {
        size_t o8 = t8 - 13631488;
        int o = (int)(o8 >> 12); int rem = (int)(o8 & 4095);
        int r = rem >> 10, i = rem & 1023;
        #pragma unroll
        for (int p = 0; p < 8; ++p) h[p] = f2bf_us(cw[(o << 12) + (i + p)*4 + r]);
        *(uint4*)(cw2b + o8) = *(const uint4*)h;
    } else {
        size_t o8 = t8 - 17825792;
        const float* src = pe + o8;
        float4 f0 = *(const float4*)src; float4 f1 = *(const float4*)(src + 4);
        h[0]=f2bf_us(f0.x); h[1]=f2bf_us(f0.y); h[2]=f2bf_us(f0.z); h[3]=f2bf_us(f0.w);
        h[4]=f2bf_us(f1.x); h[5]=f2bf_us(f1.y); h[6]=f2bf_us(f1.z); h[7]=f2bf_us(f1.w);
        *(uint4*)(peb + o8) = *(const uint4*)h;
    }
}

// ---------------- MFMA GEMM: C = A @ B^T (+bias) ----------------
template<int EPI, int QMODE>
__global__ __launch_bounds__(256) void gemm_mfma(
    const bf16* __restrict__ Abf, const bf16* __restrict__ Bbf,
    const float* __restrict__ bias, void* __restrict__ Cptr,
    void* __restrict__ C2, int M, int N, int K)
{
    __shared__ alignas(16) unsigned short As[128*64];
    __shared__ alignas(16) unsigned short Bs[128*64];
    const int tid = threadIdx.x, lane = tid & 63, w = tid >> 6;
    const int quad = lane >> 4, colq = lane & 15;
    const int wm = w >> 1, wn = w & 1;
    const int m0 = blockIdx.x * 128, n0 = blockIdx.y * 128;
    size_t abase;
    if (QMODE == 0)      abase = (size_t)m0 * K;
    else if (QMODE == 1) abase = ((size_t)((m0 >> 10)*KVN + TMEM + (m0 & 1023))) * 1024;
    else                 abase = ((size_t)((m0 >> 8)*KVN + CMEMN)) * 1024 + (size_t)(m0 & 255) * 4096;
    const unsigned short* Ag = (const unsigned short*)Abf + abase;
    const unsigned short* Bg = (const unsigned short*)Bbf + (size_t)n0 * K;

    const int srow0 = w*32 + (lane >> 3);
    const int sch2  = lane & 7;

    f32x4 acc[4][4];
    #pragma unroll
    for (int i = 0; i < 4; ++i)
        #pragma unroll
        for (int j = 0; j < 4; ++j) acc[i][j] = (f32x4){0.f,0.f,0.f,0.f};

    for (int k0 = 0; k0 < K; k0 += 64) {
        __syncthreads();
        #pragma unroll
        for (int c = 0; c < 4; ++c) {
            int rr = srow0 + c*8;
            int ch = sch2 ^ sw8(rr);
            gl2lds16(Ag + (size_t)rr*K + k0 + ch*8, &As[(w*32 + c*8)*64]);
            gl2lds16(Bg + (size_t)rr*K + k0 + ch*8, &Bs[(w*32 + c*8)*64]);
        }
        __syncthreads();
        short8 af[4][2], bfr[4][2];
        #pragma unroll
        for (int i = 0; i < 4; ++i) {
            af[i][0]  = ldfrag(As, wm*64 + i*16 + colq, quad);
            af[i][1]  = ldfrag(As, wm*64 + i*16 + colq, 4 + quad);
            bfr[i][0] = ldfrag(Bs, wn*64 + i*16 + colq, quad);
            bfr[i][1] = ldfrag(Bs, wn*64 + i*16 + colq, 4 + quad);
        }
        #pragma unroll
        for (int i = 0; i < 4; ++i)
            #pragma unroll
            for (int j = 0; j < 4; ++j) {
                f32x4 t = __builtin_amdgcn_mfma_f32_16x16x32_bf16(af[i][0], bfr[j][0], acc[i][j], 0, 0, 0);
                acc[i][j] = __builtin_amdgcn_mfma_f32_16x16x32_bf16(af[i][1], bfr[j][1], t, 0, 0, 0);
            }
    }
    if (EPI == 2) {
        const int b = m0 / KVN;
        const int jj0 = (m0 - b*KVN) + wm*64;
        if (n0 < 1024) {            // K half -> knat [b*KVN + j][1024]
            bf16* kn = (bf16*)Cptr;
            #pragma unroll
            for (int j = 0; j < 4; ++j) {
                int col = n0 + wn*64 + j*16 + colq;
                #pragma unroll
                for (int i = 0; i < 4; ++i)
                    #pragma unroll
                    for (int r = 0; r < 4; ++r)
                        kn[(size_t)(b*KVN + jj0 + i*16 + quad*4 + r)*1024 + col] =
                            __float2bfloat16(acc[i][j][r]);
            }
        } else {                    // V half -> Vh [((b*16+h)*64+d)*KVN + j]
            unsigned short* vp = (unsigned short*)C2;
            #pragma unroll
            for (int j = 0; j < 4; ++j) {
                int col = n0 + wn*64 + j*16 + colq;
                int hh = (col >> 6) & 15, d = col & 63;
                #pragma unroll
                for (int i = 0; i < 4; ++i) {
                    int jjb = jj0 + i*16 + quad*4;
                    ushort4 u;
                    u.x = f2bf_us(acc[i][j][0]); u.y = f2bf_us(acc[i][j][1]);
                    u.z = f2bf_us(acc[i][j][2]); u.w = f2bf_us(acc[i][j][3]);
                    *(ushort4*)(vp + ((size_t)((b*16 + hh)*64 + d))*KVN + jjb) = u;
                }
            }
        }
    } else {
        #pragma unroll
        for (int j = 0; j < 4; ++j) {
            int col = n0 + wn*64 + j*16 + colq;
            float bj = bias ? bias[col] : 0.0f;
            #pragma unroll
            for (int i = 0; i < 4; ++i)
                #pragma unroll
                for (int r = 0; r < 4; ++r) {
                    size_t row = (size_t)(m0 + wm*64 + i*16 + quad*4 + r);
                    float v = acc[i][j][r] + bj;
                    if (EPI == 1) ((bf16*)Cptr)[row*N + col] = __float2bfloat16(v);
                    else          ((float*)Cptr)[row*N + col] = v;
                }
        }
    }
}

// ---------------- Flash attention: 8-wave blocks, shared-LDS amortized ----------------
// Grid 512 x 512 threads. Block = (b,h,q128); wave w owns 16 q rows. Same LDS
// tiles as the 4-wave version (K dbuf, V single-buf, PE ring, Pb) now feed 8
// waves -> 16 waves/CU at 2 blocks/CU. All bulk operands via global_load_lds
// (ZERO VGPR cost -- round-1/round-4 spill lesson). Counted vmcnt: issue order
// per tile is [V(t+1), PE(t+1), K(t+2)] so barrier A waits vmcnt(1) (only
// K(t+2) in flight); vmcnt(0) on the last tile only.
// Pairing remap: blocks bx and bx+256 co-reside on a CU (round-robin CP);
// give them complementary q-tiles (p, 7-p) so each CU totals ~58 KV tiles.
__global__ __launch_bounds__(512, 4) void attn(
    const unsigned short* __restrict__ qg,   // prescaled q bf16, [b*1024+i][1024]
    const unsigned short* __restrict__ kq,   // knat [b*KVN+j][1024]
    const unsigned short* __restrict__ vh,   // Vh [((b*16+h)*64+d)][KVN]
    const unsigned short* __restrict__ peb,  // [h][KVN][64] bf16
    bf16* __restrict__ out)                  // ao [b*1024+i][1024]
{
    __shared__ alignas(16) unsigned short Kt[2][64*64];  // 16 KB dbuf
    __shared__ alignas(16) unsigned short Vt[64*64];     //  8 KB single buf, Vt[d][j]
    __shared__ alignas(16) unsigned short PEr[256*64];   // 32 KB ring
    __shared__ alignas(16) unsigned short Pb[128*64];    // 16 KB per-wave P slabs

    const int tid  = threadIdx.x;
    const int lane = tid & 63, w = tid >> 6;      // w in 0..7
    const int quad = lane >> 4, colq = lane & 15;
    const int jr = lane >> 3, l7 = lane & 7;

    const int bx = blockIdx.x;
    const int bh = bx & 63;
    const int b = bh & 3, h = bh >> 2;
    const int pp = bx >> 6;                       // 0..7
    const int qt = (pp < 4) ? pp : 11 - pp;       // pairing: (p, 7-p) share a CU
    const int q0 = qt * 128;
    const int i0 = q0 + 16*w;                     // this wave's first q row

    const unsigned short* kbase = kq  + (size_t)b*KVN*1024 + h*64;
    const unsigned short* vbase = vh  + ((size_t)((b*16 + h)*64))*KVN;
    const unsigned short* pbase = peb + (size_t)h*KVN*64;

    // Q fragments direct from global (2 loads, oldest in vm queue)
    const unsigned short* qp = qg + ((size_t)(b*1024 + i0 + colq))*1024 + h*64;
    const short8 qa0 = ldg8(qp + quad*8);
    const short8 qa1 = ldg8(qp + 32 + quad*8);

    // staging geometry: 512 threads cover a full 64x64 tile in ONE gl2lds each
    const int row = w*8 + jr;                     // 0..63
    const int ch  = (l7 ^ sw8(row))*8;

    auto stage_k = [&](int kv0s, int buf) {
        gl2lds16(kbase + (size_t)(kv0s + row)*1024 + ch, &Kt[buf][(w*8)*64]);
    };
    auto stage_v = [&](int kv0s) {
        gl2lds16(vbase + (size_t)row*KVN + kv0s + ch, &Vt[(w*8)*64]);
    };
    auto stage_pe = [&](int cbase) {              // 64 ring rows [cbase, cbase+64)
        int cg = cbase + row;
        gl2lds16(pbase + (size_t)min(cg, KVN-1)*64 + (l7 ^ sw8(cg & 255))*8,
                 &PEr[((cbase + w*8) & 255)*64]);
    };

    // prologue FIFO: [qa x2] PEfill x2, PE(tile0 top), K0, V0, K1
    const int c0p = 896 - q0;
    #pragma unroll
    for (int c = 0; c < 2; ++c) {
        int cg = c0p + c*64 + row;                // in [0, 1024), no clamp needed
        gl2lds16(pbase + (size_t)cg*64 + (l7 ^ sw8(cg & 255))*8,
                 &PEr[((c0p + c*64 + w*8) & 255)*64]);
    }
    stage_pe(1024 - q0);
    stage_k(0, 0);
    stage_v(0);
    stage_k(64, 1);
    __builtin_amdgcn_sched_barrier(0);

    f32x4 oacc[4];
    float l_[4];
    #pragma unroll
    for (int dt = 0; dt < 4; ++dt) oacc[dt] = (f32x4){0.f,0.f,0.f,0.f};
    #pragma unroll
    for (int r = 0; r < 4; ++r) l_[r] = 0.f;
    const f32x4 zero4 = (f32x4){0.f,0.f,0.f,0.f};

    const int nkv = min(36, ((q0 + 1407) >> 6) + 1);   // block-uniform causal bound
    int cur = 0;

    for (int kvt = 0; kvt < nkv; ++kvt) {
        const int kv0 = kvt * 64;
        // barrier A: K(t), V(t), PE(t) landed; K(t+2-ish) allowed in flight
        if (kvt == nkv - 1) { asm volatile("s_waitcnt vmcnt(0)" ::: "memory"); }
        else                { asm volatile("s_waitcnt vmcnt(1)" ::: "memory"); }
        __builtin_amdgcn_s_barrier();

        const unsigned short* KtC = &Kt[cur][0];
        short8 kf[4][2], vf[4][2];
        #pragma unroll
        for (int nt = 0; nt < 4; ++nt) {
            kf[nt][0] = ldfrag(KtC, nt*16 + colq, quad);
            kf[nt][1] = ldfrag(KtC, nt*16 + colq, 4 + quad);
            vf[nt][0] = ldfrag(Vt, nt*16 + colq, quad);
            vf[nt][1] = ldfrag(Vt, nt*16 + colq, 4 + quad);
        }
        asm volatile("s_waitcnt lgkmcnt(0)" ::: "memory");
        __builtin_amdgcn_s_barrier();        // barrier B: all waves done reading

        // issue next stages into freed buffers; order [V, PE, K] for vmcnt(1)
        if (kvt + 1 < nkv) { stage_v(kv0 + 64); stage_pe(kv0 + 64 - q0 + 1024); }
        if (kvt + 2 < nkv) stage_k(kv0 + 128, cur);
        __builtin_amdgcn_sched_barrier(0);

        // ---- MFMA phase: S = Q.K^T and pos band ----
        f32x4 facc[4], pacc[5];
        __builtin_amdgcn_s_setprio(1);
        #pragma unroll
        for (int nt = 0; nt < 4; ++nt) {
            f32x4 t = __builtin_amdgcn_mfma_f32_16x16x32_bf16(qa0, kf[nt][0], zero4, 0, 0, 0);
            facc[nt] = __builtin_amdgcn_mfma_f32_16x16x32_bf16(qa1, kf[nt][1], t, 0, 0, 0);
        }
        const int cb = kv0 - i0 + 1008;
        #pragma unroll
        for (int pnt = 0; pnt < 5; ++pnt) {
            int slot = (cb + pnt*16 + colq) & 255;
            short8 b0 = ldfrag(PEr, slot, quad);
            short8 b1 = ldfrag(PEr, slot, 4 + quad);
            f32x4 t = __builtin_amdgcn_mfma_f32_16x16x32_bf16(qa0, b0, zero4, 0, 0, 0);
            pacc[pnt] = __builtin_amdgcn_mfma_f32_16x16x32_bf16(qa1, b1, t, 0, 0, 0);
        }
        __builtin_amdgcn_s_setprio(0);

        // ---- softmax: gather + exp2 + P write (static-max, l deferred) ----
        const int prow0 = 16*w + 4*quad;
        #pragma unroll
        for (int r = 0; r < 4; ++r) {
            int tt = colq + 15 - 4*quad - r;
            int src = (lane & 48) | (tt & 15);
            float sh[5];
            #pragma unroll
            for (int p = 0; p < 5; ++p) sh[p] = __shfl(pacc[p][r], src, 64);
            int ig = i0 + 4*quad + r;
            float lsum = 0.f;
            float ps[4];
            #pragma unroll
            for (int nt = 0; nt < 4; ++nt) {
                float g = (tt < 16) ? sh[nt] : sh[nt + 1];
                float v = facc[nt][r] + g;
                int jg = kv0 + nt*16 + colq;
                float s = (jg - ig > TMEM) ? -1e30f : v;
                ps[nt] = __builtin_exp2f(s);   // log2e folded into q prescale
                lsum += ps[nt];
            }
            l_[r] += lsum;
            int prow = prow0 + r;
            int swp = sw8(prow);
            #pragma unroll
            for (int nt = 0; nt < 4; ++nt) {
                int cc = nt*16 + colq;
                Pb[prow*64 + (((cc >> 3) ^ swp))*8 + (cc & 7)] = f2bf_us(ps[nt]);
            }
        }
        // ---- PV (same-wave DS ordering: own writes visible to own reads) ----
        short8 pa0 = ldfrag(Pb, 16*w + colq, quad);
        short8 pa1 = ldfrag(Pb, 16*w + colq, 4 + quad);
        __builtin_amdgcn_s_setprio(1);
        #pragma unroll
        for (int dt = 0; dt < 4; ++dt) {
            f32x4 t = __builtin_amdgcn_mfma_f32_16x16x32_bf16(pa0, vf[dt][0], oacc[dt], 0, 0, 0);
            oacc[dt] = __builtin_amdgcn_mfma_f32_16x16x32_bf16(pa1, vf[dt][1], t, 0, 0, 0);
        }
        __builtin_amdgcn_s_setprio(0);
        cur ^= 1;
    }

    // ---- epilogue: reduce l across 16 colq lanes, normalize, store ----
    #pragma unroll
    for (int r = 0; r < 4; ++r) {
        float lt = l_[r];
        #pragma unroll
        for (int off = 1; off < 16; off <<= 1) lt += __shfl_xor(lt, off, 64);
        float inv = 1.0f / lt;
        size_t row_ = (size_t)(b*1024 + i0 + 4*quad + r);
        #pragma unroll
        for (int dt = 0; dt < 4; ++dt)
            out[row_*1024 + h*64 + dt*16 + colq] = __float2bfloat16(oacc[dt][r] * inv);
    }
}

// new_mem = x (fp32 bit copy, 16 MB)
__global__ __launch_bounds__(256) void copy_u4(const uint4* __restrict__ src,
                                               uint4* __restrict__ dst, int n)
{
    int i = blockIdx.x * 256 + threadIdx.x;
    if (i < n) dst[i] = src[i];
}

extern "C" void kernel_launch(void* const* d_in, const int* in_sizes, int n_in,
                              void* d_out, int out_size, void* d_ws, size_t ws_size,
                              hipStream_t stream)
{
    const float* x    = (const float*)d_in[0];
    const float* memp = (const float*)d_in[1];
    const float* cmem = (const float*)d_in[2];
    const float* pe   = (const float*)d_in[3];
    const float* Wq   = (const float*)d_in[5];
    const float* Wkv  = (const float*)d_in[6];
    const float* Wout = (const float*)d_in[7];
    const float* bout = (const float*)d_in[8];
    const float* cw   = (const float*)d_in[9];
    const float* cb   = (const float*)d_in[10];
    float* outp = (float*)d_out;

    // ws layout (bytes), total ~94.9 MB
    char* wsb = (char*)d_ws;
    unsigned short* kvin  = (unsigned short*)(wsb);              // 18,874,368
    unsigned short* knat  = (unsigned short*)(wsb + 18874368);   // 18,874,368
    unsigned short* vhb   = (unsigned short*)(wsb + 37748736);   // 18,874,368
    unsigned short* qb    = (unsigned short*)(wsb + 56623104);   //  8,388,608
    bf16*           ao    = (bf16*)(wsb + 65011712);             //  8,388,608
    unsigned short* wqb   = (unsigned short*)(wsb + 73400320);   //  2,097,152
    unsigned short* wkvb  = (unsigned short*)(wsb + 75497472);   //  4,194,304
    unsigned short* woutb = (unsigned short*)(wsb + 79691776);   //  2,097,152
    unsigned short* cw2b  = (unsigned short*)(wsb + 81788928);   //  8,388,608
    unsigned short* peb   = (unsigned short*)(wsb + 90177536);   //  4,718,592

    // stage all bf16 operands (incl. prescaled Wq with log2e, bf16 pe)
    pack<<<dim3(9856), 256, 0, stream>>>(x, memp, cmem, Wq, Wkv, Wout, cw, pe,
        kvin, wqb, wkvb, woutb, cw2b, peb);
    // q = x @ (0.125*log2e*Wq)^T  (bf16, prescaled)
    gemm_mfma<1,1><<<dim3(32, 8), 256, 0, stream>>>((const bf16*)kvin, (const bf16*)wqb,
        nullptr, qb, nullptr, 4096, 1024, 1024);
    // kv = kvin @ Wkv^T -> K natural (knat), V transposed (vhb)
    gemm_mfma<2,0><<<dim3(72, 16), 256, 0, stream>>>((const bf16*)kvin, (const bf16*)wkvb,
        nullptr, knat, vhb, 9216, 2048, 1024);
    // flash attention -> ao  (512 blocks x 512 threads; CU-paired q-tiles)
    attn<<<dim3(512), 512, 0, stream>>>(qb, knat, vhb, peb, ao);
    // logits = ao @ Wout^T + bout -> d_out (fp32)
    gemm_mfma<0,0><<<dim3(32, 8), 256, 0, stream>>>(ao, (const bf16*)woutb,
        bout, outp, nullptr, 4096, 1024, 1024);
    // new_mem = x
    copy_u4<<<dim3(4096), 256, 0, stream>>>((const uint4*)x,
        (uint4*)(outp + 4194304), 1048576);
    // new_cmem = conv(mem) as GEMM (mem-region of kvin as 1024x4096)
    gemm_mfma<0,2><<<dim3(8, 8), 256, 0, stream>>>((const bf16*)kvin, (const bf16*)cw2b,
        cb, outp + 8388608, nullptr, 1024, 1024, 4096);
}

// Round 6
// 526.095 us; speedup vs baseline: 1.4656x; 1.3809x over previous
//
#include <hip/hip_runtime.h>
#include <hip/hip_bf16.h>
#include <hip/hip_fp16.h>
#include <cstdint>
#include <cstddef>
#include <cstring>

using bf16 = __hip_bfloat16;

constexpr int TS    = 1024;
constexpr int DIM   = 1024;
constexpr int MEMN  = 1024;
constexpr int CMEMN = 256;
constexpr int KVN   = 2304;   // CMEM + MEM + T
constexpr int TMEM  = 1280;   // MEM + CMEM

typedef __attribute__((ext_vector_type(8))) short short8;
typedef __attribute__((ext_vector_type(4))) float f32x4;

__device__ __forceinline__ unsigned short f2bf_us(float f){
    __hip_bfloat16 t = __float2bfloat16(f);
    unsigned short us; memcpy(&us, &t, 2); return us;
}
__device__ __forceinline__ int sw8(int row){ return (row & 7) ^ ((row >> 3) & 7); }

// XOR-swizzled LDS tile (rows of 64 shorts, swizzle on 8-short chunks)
__device__ __forceinline__ short8 ldfrag(const unsigned short* base, int row, int chunk) {
    int ch = chunk ^ sw8(row);
    return *(const short8*)(base + row*64 + ch*8);
}
__device__ __forceinline__ void gl2lds16(const void* g, void* l) {
    __builtin_amdgcn_global_load_lds(
        (const __attribute__((address_space(1))) void*)g,
        (__attribute__((address_space(3))) void*)l, 16, 0, 0);
}
__device__ __forceinline__ short8 ldg8(const unsigned short* p){ return *(const short8*)p; }

// ---------------- pack: fp32 -> bf16 staging ----------------
__global__ __launch_bounds__(256) void pack(
    const float* __restrict__ x, const float* __restrict__ memp,
    const float* __restrict__ cmem, const float* __restrict__ Wq,
    const float* __restrict__ Wkv, const float* __restrict__ Wout,
    const float* __restrict__ cw, const float* __restrict__ pe,
    unsigned short* __restrict__ kvin, unsigned short* __restrict__ wqb,
    unsigned short* __restrict__ wkvb, unsigned short* __restrict__ woutb,
    unsigned short* __restrict__ cw2b, unsigned short* __restrict__ peb)
{
    const size_t t8 = ((size_t)blockIdx.x * 256 + threadIdx.x) * 8;
    unsigned short h[8];
    if (t8 < 9437184) {
        size_t g = t8 >> 10;
        int cc = (int)(t8 & 1023);
        int b = (int)(g / KVN), j = (int)(g % KVN);
        const float* src;
        if (j < CMEMN)      src = cmem + ((size_t)b*CMEMN + j)*1024 + cc;
        else if (j < TMEM)  src = memp + ((size_t)b*MEMN + (j - CMEMN))*1024 + cc;
        else                src = x    + ((size_t)b*TS   + (j - TMEM))*1024 + cc;
        float4 f0 = *(const float4*)src; float4 f1 = *(const float4*)(src + 4);
        h[0]=f2bf_us(f0.x); h[1]=f2bf_us(f0.y); h[2]=f2bf_us(f0.z); h[3]=f2bf_us(f0.w);
        h[4]=f2bf_us(f1.x); h[5]=f2bf_us(f1.y); h[6]=f2bf_us(f1.z); h[7]=f2bf_us(f1.w);
        *(uint4*)(kvin + t8) = *(const uint4*)h;
    } else if (t8 < 13631488) {
        const float* src; unsigned short* dst; float sc = 1.0f;
        // Wq prescale: attn scale (1/8) x log2(e) so softmax can use exp2 directly
        if (t8 < 10485760)      { src = Wq   + (t8 - 9437184);  dst = wqb   + (t8 - 9437184); sc = 0.18033688011112043f; }
        else if (t8 < 12582912) { src = Wkv  + (t8 - 10485760); dst = wkvb  + (t8 - 10485760); }
        else                    { src = Wout + (t8 - 12582912); dst = woutb + (t8 - 12582912); }
        float4 f0 = *(const float4*)src; float4 f1 = *(const float4*)(src + 4);
        h[0]=f2bf_us(f0.x*sc); h[1]=f2bf_us(f0.y*sc); h[2]=f2bf_us(f0.z*sc); h[3]=f2bf_us(f0.w*sc);
        h[4]=f2bf_us(f1.x*sc); h[5]=f2bf_us(f1.y*sc); h[6]=f2bf_us(f1.z*sc); h[7]=f2bf_us(f1.w*sc);
        *(uint4*)dst = *(const uint4*)h;
    } else if (t8 < 17825792) {
        size_t o8 = t8 - 13631488;
        int o = (int)(o8 >> 12); int rem = (int)(o8 & 4095);
        int r = rem >> 10, i = rem & 1023;
        #pragma unroll
        for (int p = 0; p < 8; ++p) h[p] = f2bf_us(cw[(o << 12) + (i + p)*4 + r]);
        *(uint4*)(cw2b + o8) = *(const uint4*)h;
    } else {
        size_t o8 = t8 - 17825792;
        const float* src = pe + o8;
        float4 f0 = *(const float4*)src; float4 f1 = *(const float4*)(src + 4);
        h[0]=f2bf_us(f0.x); h[1]=f2bf_us(f0.y); h[2]=f2bf_us(f0.z); h[3]=f2bf_us(f0.w);
        h[4]=f2bf_us(f1.x); h[5]=f2bf_us(f1.y); h[6]=f2bf_us(f1.z); h[7]=f2bf_us(f1.w);
        *(uint4*)(peb + o8) = *(const uint4*)h;
    }
}

// ---------------- MFMA GEMM: C = A @ B^T (+bias) ----------------
template<int EPI, int QMODE>
__global__ __launch_bounds__(256) void gemm_mfma(
    const bf16* __restrict__ Abf, const bf16* __restrict__ Bbf,
    const float* __restrict__ bias, void* __restrict__ Cptr,
    void* __restrict__ C2, int M, int N, int K)
{
    __shared__ alignas(16) unsigned short As[128*64];
    __shared__ alignas(16) unsigned short Bs[128*64];
    const int tid = threadIdx.x, lane = tid & 63, w = tid >> 6;
    const int quad = lane >> 4, colq = lane & 15;
    const int wm = w >> 1, wn = w & 1;
    const int m0 = blockIdx.x * 128, n0 = blockIdx.y * 128;
    size_t abase;
    if (QMODE == 0)      abase = (size_t)m0 * K;
    else if (QMODE == 1) abase = ((size_t)((m0 >> 10)*KVN + TMEM + (m0 & 1023))) * 1024;
    else                 abase = ((size_t)((m0 >> 8)*KVN + CMEMN)) * 1024 + (size_t)(m0 & 255) * 4096;
    const unsigned short* Ag = (const unsigned short*)Abf + abase;
    const unsigned short* Bg = (const unsigned short*)Bbf + (size_t)n0 * K;

    const int srow0 = w*32 + (lane >> 3);
    const int sch2  = lane & 7;

    f32x4 acc[4][4];
    #pragma unroll
    for (int i = 0; i < 4; ++i)
        #pragma unroll
        for (int j = 0; j < 4; ++j) acc[i][j] = (f32x4){0.f,0.f,0.f,0.f};

    for (int k0 = 0; k0 < K; k0 += 64) {
        __syncthreads();
        #pragma unroll
        for (int c = 0; c < 4; ++c) {
            int rr = srow0 + c*8;
            int ch = sch2 ^ sw8(rr);
            gl2lds16(Ag + (size_t)rr*K + k0 + ch*8, &As[(w*32 + c*8)*64]);
            gl2lds16(Bg + (size_t)rr*K + k0 + ch*8, &Bs[(w*32 + c*8)*64]);
        }
        __syncthreads();
        short8 af[4][2], bfr[4][2];
        #pragma unroll
        for (int i = 0; i < 4; ++i) {
            af[i][0]  = ldfrag(As, wm*64 + i*16 + colq, quad);
            af[i][1]  = ldfrag(As, wm*64 + i*16 + colq, 4 + quad);
            bfr[i][0] = ldfrag(Bs, wn*64 + i*16 + colq, quad);
            bfr[i][1] = ldfrag(Bs, wn*64 + i*16 + colq, 4 + quad);
        }
        #pragma unroll
        for (int i = 0; i < 4; ++i)
            #pragma unroll
            for (int j = 0; j < 4; ++j) {
                f32x4 t = __builtin_amdgcn_mfma_f32_16x16x32_bf16(af[i][0], bfr[j][0], acc[i][j], 0, 0, 0);
                acc[i][j] = __builtin_amdgcn_mfma_f32_16x16x32_bf16(af[i][1], bfr[j][1], t, 0, 0, 0);
            }
    }
    if (EPI == 2) {
        const int b = m0 / KVN;
        const int jj0 = (m0 - b*KVN) + wm*64;
        if (n0 < 1024) {            // K half -> knat [b*KVN + j][1024]
            bf16* kn = (bf16*)Cptr;
            #pragma unroll
            for (int j = 0; j < 4; ++j) {
                int col = n0 + wn*64 + j*16 + colq;
                #pragma unroll
                for (int i = 0; i < 4; ++i)
                    #pragma unroll
                    for (int r = 0; r < 4; ++r)
                        kn[(size_t)(b*KVN + jj0 + i*16 + quad*4 + r)*1024 + col] =
                            __float2bfloat16(acc[i][j][r]);
            }
        } else {                    // V half -> Vh [((b*16+h)*64+d)*KVN + j]
            unsigned short* vp = (unsigned short*)C2;
            #pragma unroll
            for (int j = 0; j < 4; ++j) {
                int col = n0 + wn*64 + j*16 + colq;
                int hh = (col >> 6) & 15, d = col & 63;
                #pragma unroll
                for (int i = 0; i < 4; ++i) {
                    int jjb = jj0 + i*16 + quad*4;
                    ushort4 u;
                    u.x = f2bf_us(acc[i][j][0]); u.y = f2bf_us(acc[i][j][1]);
                    u.z = f2bf_us(acc[i][j][2]); u.w = f2bf_us(acc[i][j][3]);
                    *(ushort4*)(vp + ((size_t)((b*16 + hh)*64 + d))*KVN + jjb) = u;
                }
            }
        }
    } else {
        #pragma unroll
        for (int j = 0; j < 4; ++j) {
            int col = n0 + wn*64 + j*16 + colq;
            float bj = bias ? bias[col] : 0.0f;
            #pragma unroll
            for (int i = 0; i < 4; ++i)
                #pragma unroll
                for (int r = 0; r < 4; ++r) {
                    size_t row = (size_t)(m0 + wm*64 + i*16 + quad*4 + r);
                    float v = acc[i][j][r] + bj;
                    if (EPI == 1) ((bf16*)Cptr)[row*N + col] = __float2bfloat16(v);
                    else          ((float*)Cptr)[row*N + col] = v;
                }
        }
    }
}

// ---------------- Flash attention: 8-wave blocks, shared-LDS amortized ----------------
// Grid 512 x 512 threads. Block = (b,h,q128); wave w owns 16 q rows. K dbuf,
// V single-buf, PE ring, Pb LDS shared by 8 waves -> 16 waves/CU at 2 blocks/CU.
// __launch_bounds__(512, 2): 2 waves/SIMD floor -> 128-VGPR cap (round-5 lesson:
// (512,4) meant 4 waves/SIMD -> 64-VGPR cap -> catastrophic spill).
// All bulk operands via global_load_lds (zero VGPR cost). Counted vmcnt: issue
// order per tile [V(t+1), PE(t+1), K(t+2)] -> barrier A waits vmcnt(1);
// vmcnt(0) only on the last tile. Pairing remap: blocks bx, bx+256 co-reside
// (round-robin CP) with complementary q-tiles (p, 7-p) -> ~58 KV tiles per CU.
__global__ __launch_bounds__(512, 2) void attn(
    const unsigned short* __restrict__ qg,   // prescaled q bf16, [b*1024+i][1024]
    const unsigned short* __restrict__ kq,   // knat [b*KVN+j][1024]
    const unsigned short* __restrict__ vh,   // Vh [((b*16+h)*64+d)][KVN]
    const unsigned short* __restrict__ peb,  // [h][KVN][64] bf16
    bf16* __restrict__ out)                  // ao [b*1024+i][1024]
{
    __shared__ alignas(16) unsigned short Kt[2][64*64];  // 16 KB dbuf
    __shared__ alignas(16) unsigned short Vt[64*64];     //  8 KB single buf, Vt[d][j]
    __shared__ alignas(16) unsigned short PEr[256*64];   // 32 KB ring
    __shared__ alignas(16) unsigned short Pb[128*64];    // 16 KB per-wave P slabs

    const int tid  = threadIdx.x;
    const int lane = tid & 63, w = tid >> 6;      // w in 0..7
    const int quad = lane >> 4, colq = lane & 15;
    const int jr = lane >> 3, l7 = lane & 7;

    const int bx = blockIdx.x;
    const int bh = bx & 63;
    const int b = bh & 3, h = bh >> 2;
    const int pp = bx >> 6;                       // 0..7
    const int qt = (pp < 4) ? pp : 11 - pp;       // pairing: (p, 7-p) share a CU
    const int q0 = qt * 128;
    const int i0 = q0 + 16*w;                     // this wave's first q row

    const unsigned short* kbase = kq  + (size_t)b*KVN*1024 + h*64;
    const unsigned short* vbase = vh  + ((size_t)((b*16 + h)*64))*KVN;
    const unsigned short* pbase = peb + (size_t)h*KVN*64;

    // Q fragments direct from global (2 loads, oldest in vm queue)
    const unsigned short* qp = qg + ((size_t)(b*1024 + i0 + colq))*1024 + h*64;
    const short8 qa0 = ldg8(qp + quad*8);
    const short8 qa1 = ldg8(qp + 32 + quad*8);

    // staging geometry: 512 threads cover a full 64x64 tile in ONE gl2lds each
    const int row = w*8 + jr;                     // 0..63
    const int ch  = (l7 ^ sw8(row))*8;

    auto stage_k = [&](int kv0s, int buf) {
        gl2lds16(kbase + (size_t)(kv0s + row)*1024 + ch, &Kt[buf][(w*8)*64]);
    };
    auto stage_v = [&](int kv0s) {
        gl2lds16(vbase + (size_t)row*KVN + kv0s + ch, &Vt[(w*8)*64]);
    };
    auto stage_pe = [&](int cbase) {              // 64 ring rows [cbase, cbase+64)
        int cg = cbase + row;
        gl2lds16(pbase + (size_t)min(cg, KVN-1)*64 + (l7 ^ sw8(cg & 255))*8,
                 &PEr[((cbase + w*8) & 255)*64]);
    };

    // prologue FIFO: [qa x2] PEfill x2, PE(tile0 top), K0, V0, K1
    const int c0p = 896 - q0;
    #pragma unroll
    for (int c = 0; c < 2; ++c) {
        int cg = c0p + c*64 + row;                // in [0, 1024), no clamp needed
        gl2lds16(pbase + (size_t)cg*64 + (l7 ^ sw8(cg & 255))*8,
                 &PEr[((c0p + c*64 + w*8) & 255)*64]);
    }
    stage_pe(1024 - q0);
    stage_k(0, 0);
    stage_v(0);
    stage_k(64, 1);
    __builtin_amdgcn_sched_barrier(0);

    f32x4 oacc[4];
    float l_[4];
    #pragma unroll
    for (int dt = 0; dt < 4; ++dt) oacc[dt] = (f32x4){0.f,0.f,0.f,0.f};
    #pragma unroll
    for (int r = 0; r < 4; ++r) l_[r] = 0.f;
    const f32x4 zero4 = (f32x4){0.f,0.f,0.f,0.f};

    const int nkv = min(36, ((q0 + 1407) >> 6) + 1);   // block-uniform causal bound
    int cur = 0;

    for (int kvt = 0; kvt < nkv; ++kvt) {
        const int kv0 = kvt * 64;
        // barrier A: K(t), V(t), PE(t) landed; K(t+2) allowed in flight
        if (kvt == nkv - 1) { asm volatile("s_waitcnt vmcnt(0)" ::: "memory"); }
        else                { asm volatile("s_waitcnt vmcnt(1)" ::: "memory"); }
        __builtin_amdgcn_s_barrier();

        const unsigned short* KtC = &Kt[cur][0];
        short8 kf[4][2], vf[4][2];
        #pragma unroll
        for (int nt = 0; nt < 4; ++nt) {
            kf[nt][0] = ldfrag(KtC, nt*16 + colq, quad);
            kf[nt][1] = ldfrag(KtC, nt*16 + colq, 4 + quad);
            vf[nt][0] = ldfrag(Vt, nt*16 + colq, quad);
            vf[nt][1] = ldfrag(Vt, nt*16 + colq, 4 + quad);
        }
        asm volatile("s_waitcnt lgkmcnt(0)" ::: "memory");
        __builtin_amdgcn_s_barrier();        // barrier B: all waves done reading

        // issue next stages into freed buffers; order [V, PE, K] for vmcnt(1)
        if (kvt + 1 < nkv) { stage_v(kv0 + 64); stage_pe(kv0 + 64 - q0 + 1024); }
        if (kvt + 2 < nkv) stage_k(kv0 + 128, cur);
        __builtin_amdgcn_sched_barrier(0);

        // ---- MFMA phase: S = Q.K^T and pos band ----
        f32x4 facc[4], pacc[5];
        __builtin_amdgcn_s_setprio(1);
        #pragma unroll
        for (int nt = 0; nt < 4; ++nt) {
            f32x4 t = __builtin_amdgcn_mfma_f32_16x16x32_bf16(qa0, kf[nt][0], zero4, 0, 0, 0);
            facc[nt] = __builtin_amdgcn_mfma_f32_16x16x32_bf16(qa1, kf[nt][1], t, 0, 0, 0);
        }
        const int cb = kv0 - i0 + 1008;
        #pragma unroll
        for (int pnt = 0; pnt < 5; ++pnt) {
            int slot = (cb + pnt*16 + colq) & 255;
            short8 b0 = ldfrag(PEr, slot, quad);
            short8 b1 = ldfrag(PEr, slot, 4 + quad);
            f32x4 t = __builtin_amdgcn_mfma_f32_16x16x32_bf16(qa0, b0, zero4, 0, 0, 0);
            pacc[pnt] = __builtin_amdgcn_mfma_f32_16x16x32_bf16(qa1, b1, t, 0, 0, 0);
        }
        __builtin_amdgcn_s_setprio(0);

        // ---- softmax: gather + exp2 + P write (static-max, l deferred) ----
        const int prow0 = 16*w + 4*quad;
        #pragma unroll
        for (int r = 0; r < 4; ++r) {
            int tt = colq + 15 - 4*quad - r;
            int src = (lane & 48) | (tt & 15);
            float sh[5];
            #pragma unroll
            for (int p = 0; p < 5; ++p) sh[p] = __shfl(pacc[p][r], src, 64);
            int ig = i0 + 4*quad + r;
            float lsum = 0.f;
            float ps[4];
            #pragma unroll
            for (int nt = 0; nt < 4; ++nt) {
                float g = (tt < 16) ? sh[nt] : sh[nt + 1];
                float v = facc[nt][r] + g;
                int jg = kv0 + nt*16 + colq;
                float s = (jg - ig > TMEM) ? -1e30f : v;
                ps[nt] = __builtin_exp2f(s);   // log2e folded into q prescale
                lsum += ps[nt];
            }
            l_[r] += lsum;
            int prow = prow0 + r;
            int swp = sw8(prow);
            #pragma unroll
            for (int nt = 0; nt < 4; ++nt) {
                int cc = nt*16 + colq;
                Pb[prow*64 + (((cc >> 3) ^ swp))*8 + (cc & 7)] = f2bf_us(ps[nt]);
            }
        }
        // ---- PV (same-wave DS ordering: own writes visible to own reads) ----
        short8 pa0 = ldfrag(Pb, 16*w + colq, quad);
        short8 pa1 = ldfrag(Pb, 16*w + colq, 4 + quad);
        __builtin_amdgcn_s_setprio(1);
        #pragma unroll
        for (int dt = 0; dt < 4; ++dt) {
            f32x4 t = __builtin_amdgcn_mfma_f32_16x16x32_bf16(pa0, vf[dt][0], oacc[dt], 0, 0, 0);
            oacc[dt] = __builtin_amdgcn_mfma_f32_16x16x32_bf16(pa1, vf[dt][1], t, 0, 0, 0);
        }
        __builtin_amdgcn_s_setprio(0);
        cur ^= 1;
    }

    // ---- epilogue: reduce l across 16 colq lanes, normalize, store ----
    #pragma unroll
    for (int r = 0; r < 4; ++r) {
        float lt = l_[r];
        #pragma unroll
        for (int off = 1; off < 16; off <<= 1) lt += __shfl_xor(lt, off, 64);
        float inv = 1.0f / lt;
        size_t row_ = (size_t)(b*1024 + i0 + 4*quad + r);
        #pragma unroll
        for (int dt = 0; dt < 4; ++dt)
            out[row_*1024 + h*64 + dt*16 + colq] = __float2bfloat16(oacc[dt][r] * inv);
    }
}

// new_mem = x (fp32 bit copy, 16 MB)
__global__ __launch_bounds__(256) void copy_u4(const uint4* __restrict__ src,
                                               uint4* __restrict__ dst, int n)
{
    int i = blockIdx.x * 256 + threadIdx.x;
    if (i < n) dst[i] = src[i];
}

extern "C" void kernel_launch(void* const* d_in, const int* in_sizes, int n_in,
                              void* d_out, int out_size, void* d_ws, size_t ws_size,
                              hipStream_t stream)
{
    const float* x    = (const float*)d_in[0];
    const float* memp = (const float*)d_in[1];
    const float* cmem = (const float*)d_in[2];
    const float* pe   = (const float*)d_in[3];
    const float* Wq   = (const float*)d_in[5];
    const float* Wkv  = (const float*)d_in[6];
    const float* Wout = (const float*)d_in[7];
    const float* bout = (const float*)d_in[8];
    const float* cw   = (const float*)d_in[9];
    const float* cb   = (const float*)d_in[10];
    float* outp = (float*)d_out;

    // ws layout (bytes), total ~94.9 MB
    char* wsb = (char*)d_ws;
    unsigned short* kvin  = (unsigned short*)(wsb);              // 18,874,368
    unsigned short* knat  = (unsigned short*)(wsb + 18874368);   // 18,874,368
    unsigned short* vhb   = (unsigned short*)(wsb + 37748736);   // 18,874,368
    unsigned short* qb    = (unsigned short*)(wsb + 56623104);   //  8,388,608
    bf16*           ao    = (bf16*)(wsb + 65011712);             //  8,388,608
    unsigned short* wqb   = (unsigned short*)(wsb + 73400320);   //  2,097,152
    unsigned short* wkvb  = (unsigned short*)(wsb + 75497472);   //  4,194,304
    unsigned short* woutb = (unsigned short*)(wsb + 79691776);   //  2,097,152
    unsigned short* cw2b  = (unsigned short*)(wsb + 81788928);   //  8,388,608
    unsigned short* peb   = (unsigned short*)(wsb + 90177536);   //  4,718,592

    // stage all bf16 operands (incl. prescaled Wq with log2e, bf16 pe)
    pack<<<dim3(9856), 256, 0, stream>>>(x, memp, cmem, Wq, Wkv, Wout, cw, pe,
        kvin, wqb, wkvb, woutb, cw2b, peb);
    // q = x @ (0.125*log2e*Wq)^T  (bf16, prescaled)
    gemm_mfma<1,1><<<dim3(32, 8), 256, 0, stream>>>((const bf16*)kvin, (const bf16*)wqb,
        nullptr, qb, nullptr, 4096, 1024, 1024);
    // kv = kvin @ Wkv^T -> K natural (knat), V transposed (vhb)
    gemm_mfma<2,0><<<dim3(72, 16), 256, 0, stream>>>((const bf16*)kvin, (const bf16*)wkvb,
        nullptr, knat, vhb, 9216, 2048, 1024);
    // flash attention -> ao  (512 blocks x 512 threads; CU-paired q-tiles)
    attn<<<dim3(512), 512, 0, stream>>>(qb, knat, vhb, peb, ao);
    // logits = ao @ Wout^T + bout -> d_out (fp32)
    gemm_mfma<0,0><<<dim3(32, 8), 256, 0, stream>>>(ao, (const bf16*)woutb,
        bout, outp, nullptr, 4096, 1024, 1024);
    // new_mem = x
    copy_u4<<<dim3(4096), 256, 0, stream>>>((const uint4*)x,
        (uint4*)(outp + 4194304), 1048576);
    // new_cmem = conv(mem) as GEMM (mem-region of kvin as 1024x4096)
    gemm_mfma<0,2><<<dim3(8, 8), 256, 0, stream>>>((const bf16*)kvin, (const bf16*)cw2b,
        cb, outp + 8388608, nullptr, 1024, 1024, 4096);
}

// Round 7
// 519.860 us; speedup vs baseline: 1.4832x; 1.0120x over previous
//
#include <hip/hip_runtime.h>
#include <hip/hip_bf16.h>
#include <hip/hip_fp16.h>
#include <cstdint>
#include <cstddef>
#include <cstring>

using bf16 = __hip_bfloat16;

constexpr int TS    = 1024;
constexpr int DIM   = 1024;
constexpr int MEMN  = 1024;
constexpr int CMEMN = 256;
constexpr int KVN   = 2304;   // CMEM + MEM + T
constexpr int TMEM  = 1280;   // MEM + CMEM

typedef __attribute__((ext_vector_type(8))) short short8;
typedef __attribute__((ext_vector_type(4))) float f32x4;

__device__ __forceinline__ unsigned short f2bf_us(float f){
    __hip_bfloat16 t = __float2bfloat16(f);
    unsigned short us; memcpy(&us, &t, 2); return us;
}
__device__ __forceinline__ int sw8(int row){ return (row & 7) ^ ((row >> 3) & 7); }

// XOR-swizzled LDS tile (rows of 64 shorts, swizzle on 8-short chunks)
__device__ __forceinline__ short8 ldfrag(const unsigned short* base, int row, int chunk) {
    int ch = chunk ^ sw8(row);
    return *(const short8*)(base + row*64 + ch*8);
}
__device__ __forceinline__ void gl2lds16(const void* g, void* l) {
    __builtin_amdgcn_global_load_lds(
        (const __attribute__((address_space(1))) void*)g,
        (__attribute__((address_space(3))) void*)l, 16, 0, 0);
}
__device__ __forceinline__ short8 ldg8(const unsigned short* p){ return *(const short8*)p; }

// ---------------- pack: fp32 -> bf16 staging ----------------
__global__ __launch_bounds__(256) void pack(
    const float* __restrict__ x, const float* __restrict__ memp,
    const float* __restrict__ cmem, const float* __restrict__ Wq,
    const float* __restrict__ Wkv, const float* __restrict__ Wout,
    const float* __restrict__ cw, const float* __restrict__ pe,
    unsigned short* __restrict__ kvin, unsigned short* __restrict__ wqb,
    unsigned short* __restrict__ wkvb, unsigned short* __restrict__ woutb,
    unsigned short* __restrict__ cw2b, unsigned short* __restrict__ peb)
{
    const size_t t8 = ((size_t)blockIdx.x * 256 + threadIdx.x) * 8;
    unsigned short h[8];
    if (t8 < 9437184) {
        size_t g = t8 >> 10;
        int cc = (int)(t8 & 1023);
        int b = (int)(g / KVN), j = (int)(g % KVN);
        const float* src;
        if (j < CMEMN)      src = cmem + ((size_t)b*CMEMN + j)*1024 + cc;
        else if (j < TMEM)  src = memp + ((size_t)b*MEMN + (j - CMEMN))*1024 + cc;
        else                src = x    + ((size_t)b*TS   + (j - TMEM))*1024 + cc;
        float4 f0 = *(const float4*)src; float4 f1 = *(const float4*)(src + 4);
        h[0]=f2bf_us(f0.x); h[1]=f2bf_us(f0.y); h[2]=f2bf_us(f0.z); h[3]=f2bf_us(f0.w);
        h[4]=f2bf_us(f1.x); h[5]=f2bf_us(f1.y); h[6]=f2bf_us(f1.z); h[7]=f2bf_us(f1.w);
        *(uint4*)(kvin + t8) = *(const uint4*)h;
    } else if (t8 < 13631488) {
        const float* src; unsigned short* dst; float sc = 1.0f;
        // Wq prescale: attn scale (1/8) x log2(e) so softmax can use exp2 directly
        if (t8 < 10485760)      { src = Wq   + (t8 - 9437184);  dst = wqb   + (t8 - 9437184); sc = 0.18033688011112043f; }
        else if (t8 < 12582912) { src = Wkv  + (t8 - 10485760); dst = wkvb  + (t8 - 10485760); }
        else                    { src = Wout + (t8 - 12582912); dst = woutb + (t8 - 12582912); }
        float4 f0 = *(const float4*)src; float4 f1 = *(const float4*)(src + 4);
        h[0]=f2bf_us(f0.x*sc); h[1]=f2bf_us(f0.y*sc); h[2]=f2bf_us(f0.z*sc); h[3]=f2bf_us(f0.w*sc);
        h[4]=f2bf_us(f1.x*sc); h[5]=f2bf_us(f1.y*sc); h[6]=f2bf_us(f1.z*sc); h[7]=f2bf_us(f1.w*sc);
        *(uint4*)dst = *(const uint4*)h;
    } else if (t8 < 17825792) {
        size_t o8 = t8 - 13631488;
        int o = (int)(o8 >> 12); int rem = (int)(o8 & 4095);
        int r = rem >> 10, i = rem & 1023;
        #pragma unroll
        for (int p = 0; p < 8; ++p) h[p] = f2bf_us(cw[(o << 12) + (i + p)*4 + r]);
        *(uint4*)(cw2b + o8) = *(const uint4*)h;
    } else {
        size_t o8 = t8 - 17825792;
        const float* src = pe + o8;
        float4 f0 = *(const float4*)src; float4 f1 = *(const float4*)(src + 4);
        h[0]=f2bf_us(f0.x); h[1]=f2bf_us(f0.y); h[2]=f2bf_us(f0.z); h[3]=f2bf_us(f0.w);
        h[4]=f2bf_us(f1.x); h[5]=f2bf_us(f1.y); h[6]=f2bf_us(f1.z); h[7]=f2bf_us(f1.w);
        *(uint4*)(peb + o8) = *(const uint4*)h;
    }
}

// ---------------- MFMA GEMM: C = A @ B^T (+bias) ----------------
template<int EPI, int QMODE>
__global__ __launch_bounds__(256) void gemm_mfma(
    const bf16* __restrict__ Abf, const bf16* __restrict__ Bbf,
    const float* __restrict__ bias, void* __restrict__ Cptr,
    void* __restrict__ C2, int M, int N, int K)
{
    __shared__ alignas(16) unsigned short As[128*64];
    __shared__ alignas(16) unsigned short Bs[128*64];
    const int tid = threadIdx.x, lane = tid & 63, w = tid >> 6;
    const int quad = lane >> 4, colq = lane & 15;
    const int wm = w >> 1, wn = w & 1;
    const int m0 = blockIdx.x * 128, n0 = blockIdx.y * 128;
    size_t abase;
    if (QMODE == 0)      abase = (size_t)m0 * K;
    else if (QMODE == 1) abase = ((size_t)((m0 >> 10)*KVN + TMEM + (m0 & 1023))) * 1024;
    else                 abase = ((size_t)((m0 >> 8)*KVN + CMEMN)) * 1024 + (size_t)(m0 & 255) * 4096;
    const unsigned short* Ag = (const unsigned short*)Abf + abase;
    const unsigned short* Bg = (const unsigned short*)Bbf + (size_t)n0 * K;

    const int srow0 = w*32 + (lane >> 3);
    const int sch2  = lane & 7;

    f32x4 acc[4][4];
    #pragma unroll
    for (int i = 0; i < 4; ++i)
        #pragma unroll
        for (int j = 0; j < 4; ++j) acc[i][j] = (f32x4){0.f,0.f,0.f,0.f};

    for (int k0 = 0; k0 < K; k0 += 64) {
        __syncthreads();
        #pragma unroll
        for (int c = 0; c < 4; ++c) {
            int rr = srow0 + c*8;
            int ch = sch2 ^ sw8(rr);
            gl2lds16(Ag + (size_t)rr*K + k0 + ch*8, &As[(w*32 + c*8)*64]);
            gl2lds16(Bg + (size_t)rr*K + k0 + ch*8, &Bs[(w*32 + c*8)*64]);
        }
        __syncthreads();
        short8 af[4][2], bfr[4][2];
        #pragma unroll
        for (int i = 0; i < 4; ++i) {
            af[i][0]  = ldfrag(As, wm*64 + i*16 + colq, quad);
            af[i][1]  = ldfrag(As, wm*64 + i*16 + colq, 4 + quad);
            bfr[i][0] = ldfrag(Bs, wn*64 + i*16 + colq, quad);
            bfr[i][1] = ldfrag(Bs, wn*64 + i*16 + colq, 4 + quad);
        }
        #pragma unroll
        for (int i = 0; i < 4; ++i)
            #pragma unroll
            for (int j = 0; j < 4; ++j) {
                f32x4 t = __builtin_amdgcn_mfma_f32_16x16x32_bf16(af[i][0], bfr[j][0], acc[i][j], 0, 0, 0);
                acc[i][j] = __builtin_amdgcn_mfma_f32_16x16x32_bf16(af[i][1], bfr[j][1], t, 0, 0, 0);
            }
    }
    if (EPI == 2) {
        const int b = m0 / KVN;
        const int jj0 = (m0 - b*KVN) + wm*64;
        if (n0 < 1024) {            // K half -> knat [b*KVN + j][1024]
            bf16* kn = (bf16*)Cptr;
            #pragma unroll
            for (int j = 0; j < 4; ++j) {
                int col = n0 + wn*64 + j*16 + colq;
                #pragma unroll
                for (int i = 0; i < 4; ++i)
                    #pragma unroll
                    for (int r = 0; r < 4; ++r)
                        kn[(size_t)(b*KVN + jj0 + i*16 + quad*4 + r)*1024 + col] =
                            __float2bfloat16(acc[i][j][r]);
            }
        } else {                    // V half -> Vh [((b*16+h)*64+d)*KVN + j]
            unsigned short* vp = (unsigned short*)C2;
            #pragma unroll
            for (int j = 0; j < 4; ++j) {
                int col = n0 + wn*64 + j*16 + colq;
                int hh = (col >> 6) & 15, d = col & 63;
                #pragma unroll
                for (int i = 0; i < 4; ++i) {
                    int jjb = jj0 + i*16 + quad*4;
                    ushort4 u;
                    u.x = f2bf_us(acc[i][j][0]); u.y = f2bf_us(acc[i][j][1]);
                    u.z = f2bf_us(acc[i][j][2]); u.w = f2bf_us(acc[i][j][3]);
                    *(ushort4*)(vp + ((size_t)((b*16 + hh)*64 + d))*KVN + jjb) = u;
                }
            }
        }
    } else {
        #pragma unroll
        for (int j = 0; j < 4; ++j) {
            int col = n0 + wn*64 + j*16 + colq;
            float bj = bias ? bias[col] : 0.0f;
            #pragma unroll
            for (int i = 0; i < 4; ++i)
                #pragma unroll
                for (int r = 0; r < 4; ++r) {
                    size_t row = (size_t)(m0 + wm*64 + i*16 + quad*4 + r);
                    float v = acc[i][j][r] + bj;
                    if (EPI == 1) ((bf16*)Cptr)[row*N + col] = __float2bfloat16(v);
                    else          ((float*)Cptr)[row*N + col] = v;
                }
        }
    }
}

// ---------------- Flash attention: round-3 structure + V direct-global ----------------
// 512 blocks (b,h,q128) with balanced qt pairing; 4 waves x 32 q-rows (it2).
// K double-buffered + PE ring via global_load_lds (counted vmcnt, no drain in
// loop). V fragments read DIRECTLY from global at loop top (L2-resident;
// youngest in vm queue -> barrier-A wait is vmcnt(10); compiler's auto-wait
// before PV is a counted vmcnt(4) leaving staging in flight). This removes
// 8 of 40 ds_read_b128 per wave-tile and 16KB LDS (LDS batch is the
// measured per-tile-step bottleneck; r3 vs r6 wave-scaling null proved it).
__global__ __launch_bounds__(256, 2) void attn(
    const unsigned short* __restrict__ qg,   // prescaled q bf16, [b*1024+i][1024]
    const unsigned short* __restrict__ kq,   // knat [b*KVN+j][1024]
    const unsigned short* __restrict__ vh,   // Vh [((b*16+h)*64+d)][KVN]
    const unsigned short* __restrict__ peb,  // [h][KVN][64] bf16
    bf16* __restrict__ out)                  // ao [b*1024+i][1024]
{
    __shared__ alignas(16) unsigned short Kt[2][64*64];  // 16 KB dbuf
    __shared__ alignas(16) unsigned short PEr[256*64];   // 32 KB ring
    __shared__ alignas(16) unsigned short Pb[64*64];     //  8 KB per-wave P slab

    const int tid  = threadIdx.x;
    const int lane = tid & 63, w = tid >> 6;
    const int quad = lane >> 4, colq = lane & 15;
    const int jr = lane >> 3, l7 = lane & 7;

    const int bx = blockIdx.x;
    const int b = bx & 3, h = (bx >> 2) & 15;
    const int pp = bx >> 6;                   // 0..7; bx and bx+256 share a CU
    const int qt = (pp < 4) ? pp : 11 - pp;   // pairs (p,7-p): 58 tiles per CU
    const int q0 = qt * 128;

    const unsigned short* kbase = kq  + (size_t)b*KVN*1024 + h*64;
    const unsigned short* vbase = vh  + ((size_t)((b*16 + h)*64))*KVN;
    const unsigned short* pbase = peb + (size_t)h*KVN*64;

    // Q fragments direct from global (oldest in vm queue)
    short8 qa[2][2];
    #pragma unroll
    for (int it2 = 0; it2 < 2; ++it2) {
        const unsigned short* qp = qg + ((size_t)(b*1024 + q0 + 32*w + 16*it2 + colq))*1024 + h*64;
        qa[it2][0] = ldg8(qp + quad*8);
        qa[it2][1] = ldg8(qp + 32 + quad*8);
    }
    __builtin_amdgcn_sched_barrier(0);   // pin qa loads before staging issues

    const int row0 = w*8 + jr;           // 0..31
    const int row1 = 32 + row0;          // 32..63
    const int ch0 = (l7 ^ sw8(row0))*8;
    const int ch1 = (l7 ^ sw8(row1))*8;

    auto stage_k = [&](int kv0s, int buf) {
        gl2lds16(kbase + (size_t)(kv0s + row0)*1024 + ch0, &Kt[buf][(w*8)*64]);
        gl2lds16(kbase + (size_t)(kv0s + row1)*1024 + ch1, &Kt[buf][(32 + w*8)*64]);
    };
    auto stage_pe = [&](int cbase) {     // 64 ring rows [cbase, cbase+64)
        int cg0 = cbase + row0, cg1 = cbase + row1;
        gl2lds16(pbase + (size_t)min(cg0, KVN-1)*64 + (l7 ^ sw8(cg0 & 255))*8,
                 &PEr[((cbase + w*8) & 255)*64]);
        gl2lds16(pbase + (size_t)min(cg1, KVN-1)*64 + (l7 ^ sw8(cg1 & 255))*8,
                 &PEr[((cbase + 32 + w*8) & 255)*64]);
    };

    // prologue issue order: PEfill4, PE(0)2, K(0)2, K(1)2
    const int c0p = 896 - q0;
    #pragma unroll
    for (int c = 0; c < 4; ++c) {
        int cg = c0p + c*32 + w*8 + jr;
        gl2lds16(pbase + (size_t)cg*64 + (l7 ^ sw8(cg & 255))*8,
                 &PEr[((c0p + c*32 + w*8) & 255)*64]);
    }
    stage_pe(1024 - q0);
    stage_k(0, 0);
    stage_k(64, 1);
    __builtin_amdgcn_sched_barrier(0);

    f32x4 oacc[2][4];
    float l_[2][4];
    #pragma unroll
    for (int it2 = 0; it2 < 2; ++it2) {
        #pragma unroll
        for (int dt = 0; dt < 4; ++dt) oacc[it2][dt] = (f32x4){0.f,0.f,0.f,0.f};
        #pragma unroll
        for (int r = 0; r < 4; ++r) l_[it2][r] = 0.f;
    }
    const f32x4 zero4 = (f32x4){0.f,0.f,0.f,0.f};
    const int nkv = min(36, ((q0 + 1407) >> 6) + 1);
    int cur = 0;

    for (int kvt = 0; kvt < nkv; ++kvt) {
        const int kv0 = kvt * 64;
        // V fragments direct from global, issued FIRST (youngest in vm queue;
        // consumed at PV -> latency hidden under QK/PE MFMAs + softmax)
        short8 vf[4][2];
        #pragma unroll
        for (int dt = 0; dt < 4; ++dt) {
            const unsigned short* vp = vbase + (size_t)(dt*16 + colq)*KVN + kv0;
            vf[dt][0] = ldg8(vp + quad*8);
            vf[dt][1] = ldg8(vp + 32 + quad*8);
        }
        __builtin_amdgcn_sched_barrier(0);
        // barrier A: PE(t), K(t) landed; K(t+1) (2) + vf (8) stay in flight
        if (kvt == nkv - 1) { asm volatile("s_waitcnt vmcnt(8)" ::: "memory"); }
        else                { asm volatile("s_waitcnt vmcnt(10)" ::: "memory"); }
        __builtin_amdgcn_s_barrier();

        const unsigned short* KtC = &Kt[cur][0];
        short8 kf[4][2];
        #pragma unroll
        for (int nt = 0; nt < 4; ++nt) {
            kf[nt][0] = ldfrag(KtC, nt*16 + colq, quad);
            kf[nt][1] = ldfrag(KtC, nt*16 + colq, 4 + quad);
        }
        asm volatile("s_waitcnt lgkmcnt(0)" ::: "memory");
        __builtin_amdgcn_s_barrier();        // all waves done reading Kt[cur]

        // issue next stages: PE 1 ahead, K 2 ahead (into the freed buffer)
        if (kvt + 1 < nkv) stage_pe(kv0 + 64 - q0 + 1024);
        if (kvt + 2 < nkv) stage_k(kv0 + 128, cur);
        __builtin_amdgcn_sched_barrier(0);

        // ---- MFMA phase: QK + pos band for BOTH it2 halves ----
        f32x4 facc[2][4], pacc[2][5];
        __builtin_amdgcn_s_setprio(1);
        #pragma unroll
        for (int it2 = 0; it2 < 2; ++it2)
            #pragma unroll
            for (int nt = 0; nt < 4; ++nt) {
                f32x4 t = __builtin_amdgcn_mfma_f32_16x16x32_bf16(qa[it2][0], kf[nt][0], zero4, 0, 0, 0);
                facc[it2][nt] = __builtin_amdgcn_mfma_f32_16x16x32_bf16(qa[it2][1], kf[nt][1], t, 0, 0, 0);
            }
        #pragma unroll
        for (int it2 = 0; it2 < 2; ++it2) {
            const int cb = kv0 - q0 + 1008 - 32*w - 16*it2;
            #pragma unroll
            for (int pnt = 0; pnt < 5; ++pnt) {
                int slot = (cb + pnt*16 + colq) & 255;
                short8 b0 = ldfrag(PEr, slot, quad);
                short8 b1 = ldfrag(PEr, slot, 4 + quad);
                f32x4 t = __builtin_amdgcn_mfma_f32_16x16x32_bf16(qa[it2][0], b0, zero4, 0, 0, 0);
                pacc[it2][pnt] = __builtin_amdgcn_mfma_f32_16x16x32_bf16(qa[it2][1], b1, t, 0, 0, 0);
            }
        }
        __builtin_amdgcn_s_setprio(0);

        // ---- softmax + PV per it2 (P slab reused; E1 overlaps F0) ----
        #pragma unroll
        for (int it2 = 0; it2 < 2; ++it2) {
            const int prow0 = 16*w + 4*quad;
            #pragma unroll
            for (int r = 0; r < 4; ++r) {
                int tt = colq + 15 - 4*quad - r;
                int src = (lane & 48) | (tt & 15);
                float sh[5];
                #pragma unroll
                for (int p = 0; p < 5; ++p) sh[p] = __shfl(pacc[it2][p][r], src, 64);
                int ig = q0 + 32*w + 16*it2 + 4*quad + r;
                float lsum = 0.f;
                float ps[4];
                #pragma unroll
                for (int nt = 0; nt < 4; ++nt) {
                    float g = (tt < 16) ? sh[nt] : sh[nt + 1];
                    float v = facc[it2][nt][r] + g;
                    int jg = kv0 + nt*16 + colq;
                    float s = (jg - ig > TMEM) ? -1e30f : v;
                    ps[nt] = __builtin_exp2f(s);   // log2e folded into q prescale
                    lsum += ps[nt];
                }
                l_[it2][r] += lsum;
                int prow = prow0 + r;
                int swp = sw8(prow);
                #pragma unroll
                for (int nt = 0; nt < 4; ++nt) {
                    int cc = nt*16 + colq;
                    Pb[prow*64 + (((cc >> 3) ^ swp))*8 + (cc & 7)] = f2bf_us(ps[nt]);
                }
            }
            // PV (same-wave DS ordering: own writes visible to own reads)
            short8 pa0 = ldfrag(Pb, 16*w + colq, quad);
            short8 pa1 = ldfrag(Pb, 16*w + colq, 4 + quad);
            __builtin_amdgcn_s_setprio(1);
            #pragma unroll
            for (int dt = 0; dt < 4; ++dt) {
                f32x4 t = __builtin_amdgcn_mfma_f32_16x16x32_bf16(pa0, vf[dt][0], oacc[it2][dt], 0, 0, 0);
                oacc[it2][dt] = __builtin_amdgcn_mfma_f32_16x16x32_bf16(pa1, vf[dt][1], t, 0, 0, 0);
            }
            __builtin_amdgcn_s_setprio(0);
        }
        cur ^= 1;
    }

    // ---- epilogue: reduce l across 16 colq lanes, normalize, store ----
    #pragma unroll
    for (int it2 = 0; it2 < 2; ++it2) {
        #pragma unroll
        for (int r = 0; r < 4; ++r) {
            float lt = l_[it2][r];
            #pragma unroll
            for (int off = 1; off < 16; off <<= 1) lt += __shfl_xor(lt, off, 64);
            float inv = 1.0f / lt;
            size_t row = (size_t)(b*1024 + q0 + 32*w + 16*it2 + 4*quad + r);
            #pragma unroll
            for (int dt = 0; dt < 4; ++dt)
                out[row*1024 + h*64 + dt*16 + colq] = __float2bfloat16(oacc[it2][dt][r] * inv);
        }
    }
}

// new_mem = x (fp32 bit copy, 16 MB)
__global__ __launch_bounds__(256) void copy_u4(const uint4* __restrict__ src,
                                               uint4* __restrict__ dst, int n)
{
    int i = blockIdx.x * 256 + threadIdx.x;
    if (i < n) dst[i] = src[i];
}

extern "C" void kernel_launch(void* const* d_in, const int* in_sizes, int n_in,
                              void* d_out, int out_size, void* d_ws, size_t ws_size,
                              hipStream_t stream)
{
    const float* x    = (const float*)d_in[0];
    const float* memp = (const float*)d_in[1];
    const float* cmem = (const float*)d_in[2];
    const float* pe   = (const float*)d_in[3];
    const float* Wq   = (const float*)d_in[5];
    const float* Wkv  = (const float*)d_in[6];
    const float* Wout = (const float*)d_in[7];
    const float* bout = (const float*)d_in[8];
    const float* cw   = (const float*)d_in[9];
    const float* cb   = (const float*)d_in[10];
    float* outp = (float*)d_out;

    // ws layout (bytes), total ~94.9 MB
    char* wsb = (char*)d_ws;
    unsigned short* kvin  = (unsigned short*)(wsb);              // 18,874,368
    unsigned short* knat  = (unsigned short*)(wsb + 18874368);   // 18,874,368
    unsigned short* vhb   = (unsigned short*)(wsb + 37748736);   // 18,874,368
    unsigned short* qb    = (unsigned short*)(wsb + 56623104);   //  8,388,608
    bf16*           ao    = (bf16*)(wsb + 65011712);             //  8,388,608
    unsigned short* wqb   = (unsigned short*)(wsb + 73400320);   //  2,097,152
    unsigned short* wkvb  = (unsigned short*)(wsb + 75497472);   //  4,194,304
    unsigned short* woutb = (unsigned short*)(wsb + 79691776);   //  2,097,152
    unsigned short* cw2b  = (unsigned short*)(wsb + 81788928);   //  8,388,608
    unsigned short* peb   = (unsigned short*)(wsb + 90177536);   //  4,718,592

    // stage all bf16 operands (incl. prescaled Wq with log2e, bf16 pe)
    pack<<<dim3(9856), 256, 0, stream>>>(x, memp, cmem, Wq, Wkv, Wout, cw, pe,
        kvin, wqb, wkvb, woutb, cw2b, peb);
    // q = x @ (0.125*log2e*Wq)^T  (bf16, prescaled)
    gemm_mfma<1,1><<<dim3(32, 8), 256, 0, stream>>>((const bf16*)kvin, (const bf16*)wqb,
        nullptr, qb, nullptr, 4096, 1024, 1024);
    // kv = kvin @ Wkv^T -> K natural (knat), V transposed (vhb)
    gemm_mfma<2,0><<<dim3(72, 16), 256, 0, stream>>>((const bf16*)kvin, (const bf16*)wkvb,
        nullptr, knat, vhb, 9216, 2048, 1024);
    // flash attention -> ao  (512 blocks; CU-paired q-tiles)
    attn<<<dim3(512), 256, 0, stream>>>(qb, knat, vhb, peb, ao);
    // logits = ao @ Wout^T + bout -> d_out (fp32)
    gemm_mfma<0,0><<<dim3(32, 8), 256, 0, stream>>>(ao, (const bf16*)woutb,
        bout, outp, nullptr, 4096, 1024, 1024);
    // new_mem = x
    copy_u4<<<dim3(4096), 256, 0, stream>>>((const uint4*)x,
        (uint4*)(outp + 4194304), 1048576);
    // new_cmem = conv(mem) as GEMM (mem-region of kvin as 1024x4096)
    gemm_mfma<0,2><<<dim3(8, 8), 256, 0, stream>>>((const bf16*)kvin, (const bf16*)cw2b,
        cb, outp + 8388608, nullptr, 1024, 1024, 4096);
}

// Round 8
// 483.642 us; speedup vs baseline: 1.5942x; 1.0749x over previous
//
#include <hip/hip_runtime.h>
#include <hip/hip_bf16.h>
#include <hip/hip_fp16.h>
#include <cstdint>
#include <cstddef>
#include <cstring>

using bf16 = __hip_bfloat16;

constexpr int TS    = 1024;
constexpr int DIM   = 1024;
constexpr int MEMN  = 1024;
constexpr int CMEMN = 256;
constexpr int KVN   = 2304;   // CMEM + MEM + T
constexpr int TMEM  = 1280;   // MEM + CMEM

typedef __attribute__((ext_vector_type(8))) short short8;
typedef __attribute__((ext_vector_type(4))) float f32x4;

__device__ __forceinline__ unsigned short f2bf_us(float f){
    __hip_bfloat16 t = __float2bfloat16(f);
    unsigned short us; memcpy(&us, &t, 2); return us;
}
__device__ __forceinline__ int sw8(int row){ return (row & 7) ^ ((row >> 3) & 7); }

// XOR-swizzled LDS tile (rows of 64 shorts, swizzle on 8-short chunks)
__device__ __forceinline__ short8 ldfrag(const unsigned short* base, int row, int chunk) {
    int ch = chunk ^ sw8(row);
    return *(const short8*)(base + row*64 + ch*8);
}
__device__ __forceinline__ void gl2lds16(const void* g, void* l) {
    __builtin_amdgcn_global_load_lds(
        (const __attribute__((address_space(1))) void*)g,
        (__attribute__((address_space(3))) void*)l, 16, 0, 0);
}
__device__ __forceinline__ short8 ldg8(const unsigned short* p){ return *(const short8*)p; }

// ---------------- pack: fp32 -> bf16 staging ----------------
__global__ __launch_bounds__(256) void pack(
    const float* __restrict__ x, const float* __restrict__ memp,
    const float* __restrict__ cmem, const float* __restrict__ Wq,
    const float* __restrict__ Wkv, const float* __restrict__ Wout,
    const float* __restrict__ cw, const float* __restrict__ pe,
    unsigned short* __restrict__ kvin, unsigned short* __restrict__ wqb,
    unsigned short* __restrict__ wkvb, unsigned short* __restrict__ woutb,
    unsigned short* __restrict__ cw2b, unsigned short* __restrict__ peb)
{
    const size_t t8 = ((size_t)blockIdx.x * 256 + threadIdx.x) * 8;
    unsigned short h[8];
    if (t8 < 9437184) {
        size_t g = t8 >> 10;
        int cc = (int)(t8 & 1023);
        int b = (int)(g / KVN), j = (int)(g % KVN);
        const float* src;
        if (j < CMEMN)      src = cmem + ((size_t)b*CMEMN + j)*1024 + cc;
        else if (j < TMEM)  src = memp + ((size_t)b*MEMN + (j - CMEMN))*1024 + cc;
        else                src = x    + ((size_t)b*TS   + (j - TMEM))*1024 + cc;
        float4 f0 = *(const float4*)src; float4 f1 = *(const float4*)(src + 4);
        h[0]=f2bf_us(f0.x); h[1]=f2bf_us(f0.y); h[2]=f2bf_us(f0.z); h[3]=f2bf_us(f0.w);
        h[4]=f2bf_us(f1.x); h[5]=f2bf_us(f1.y); h[6]=f2bf_us(f1.z); h[7]=f2bf_us(f1.w);
        *(uint4*)(kvin + t8) = *(const uint4*)h;
    } else if (t8 < 13631488) {
        const float* src; unsigned short* dst; float sc = 1.0f;
        // Wq prescale: attn scale (1/8) x log2(e) so softmax can use exp2 directly
        if (t8 < 10485760)      { src = Wq   + (t8 - 9437184);  dst = wqb   + (t8 - 9437184); sc = 0.18033688011112043f; }
        else if (t8 < 12582912) { src = Wkv  + (t8 - 10485760); dst = wkvb  + (t8 - 10485760); }
        else                    { src = Wout + (t8 - 12582912); dst = woutb + (t8 - 12582912); }
        float4 f0 = *(const float4*)src; float4 f1 = *(const float4*)(src + 4);
        h[0]=f2bf_us(f0.x*sc); h[1]=f2bf_us(f0.y*sc); h[2]=f2bf_us(f0.z*sc); h[3]=f2bf_us(f0.w*sc);
        h[4]=f2bf_us(f1.x*sc); h[5]=f2bf_us(f1.y*sc); h[6]=f2bf_us(f1.z*sc); h[7]=f2bf_us(f1.w*sc);
        *(uint4*)dst = *(const uint4*)h;
    } else if (t8 < 17825792) {
        size_t o8 = t8 - 13631488;
        int o = (int)(o8 >> 12); int rem = (int)(o8 & 4095);
        int r = rem >> 10, i = rem & 1023;
        #pragma unroll
        for (int p = 0; p < 8; ++p) h[p] = f2bf_us(cw[(o << 12) + (i + p)*4 + r]);
        *(uint4*)(cw2b + o8) = *(const uint4*)h;
    } else {
        size_t o8 = t8 - 17825792;
        const float* src = pe + o8;
        float4 f0 = *(const float4*)src; float4 f1 = *(const float4*)(src + 4);
        h[0]=f2bf_us(f0.x); h[1]=f2bf_us(f0.y); h[2]=f2bf_us(f0.z); h[3]=f2bf_us(f0.w);
        h[4]=f2bf_us(f1.x); h[5]=f2bf_us(f1.y); h[6]=f2bf_us(f1.z); h[7]=f2bf_us(f1.w);
        *(uint4*)(peb + o8) = *(const uint4*)h;
    }
}

// ---------------- MFMA GEMM: C = A @ B^T (+bias) ----------------
// Templated tile: BM x NB (128x128, 64x128, 64x64). Hot K-loop unchanged
// (m97-style single buffer: dbuf's 64KB LDS costs a resident block, net loss).
// EPI 0: fp32 out (+bias). 1: bf16 out. 2 (BM=NB=128): kv split -> knat +
//   V-half via LDS transpose -> COALESCED 16B stores (was 8B scattered).
// QMODE 0: A rows contiguous. 1: x-region of kvin. 2: mem-region as 1024x4096.
template<int EPI, int QMODE, int BM, int NB>
__global__ __launch_bounds__(256) void gemm_mfma(
    const bf16* __restrict__ Abf, const bf16* __restrict__ Bbf,
    const float* __restrict__ bias, void* __restrict__ Cptr,
    void* __restrict__ C2, int M, int N, int K)
{
    constexpr int MI = (BM == 128) ? 4 : 2;   // A-fragment repeats per wave
    constexpr int NJ = (NB == 128) ? 4 : 2;   // B-fragment repeats per wave
    constexpr int WROWS = BM / 2;             // rows per wm
    constexpr int WCOLS = NB / 2;             // cols per wn
    __shared__ alignas(16) unsigned short Sh[(BM + NB) * 64];
    unsigned short* As = Sh;
    unsigned short* Bs = Sh + BM*64;

    const int tid = threadIdx.x, lane = tid & 63, w = tid >> 6;
    const int quad = lane >> 4, colq = lane & 15;
    const int wm = w >> 1, wn = w & 1;
    const int jr = lane >> 3, l7 = lane & 7;
    const int m0 = blockIdx.x * BM, n0 = blockIdx.y * NB;
    size_t abase;
    if (QMODE == 0)      abase = (size_t)m0 * K;
    else if (QMODE == 1) abase = ((size_t)((m0 >> 10)*KVN + TMEM + (m0 & 1023))) * 1024;
    else                 abase = ((size_t)((m0 >> 8)*KVN + CMEMN)) * 1024 + (size_t)(m0 & 255) * 4096;
    const unsigned short* Ag = (const unsigned short*)Abf + abase;
    const unsigned short* Bg = (const unsigned short*)Bbf + (size_t)n0 * K;

    f32x4 acc[MI][NJ];
    #pragma unroll
    for (int i = 0; i < MI; ++i)
        #pragma unroll
        for (int j = 0; j < NJ; ++j) acc[i][j] = (f32x4){0.f,0.f,0.f,0.f};

    for (int k0 = 0; k0 < K; k0 += 64) {
        __syncthreads();
        #pragma unroll
        for (int c = 0; c < BM/32; ++c) {
            int rr = w*(BM/4) + c*8 + jr;
            int ch = l7 ^ sw8(rr);
            gl2lds16(Ag + (size_t)rr*K + k0 + ch*8, &As[(w*(BM/4) + c*8)*64]);
        }
        #pragma unroll
        for (int c = 0; c < NB/32; ++c) {
            int rr = w*(NB/4) + c*8 + jr;
            int ch = l7 ^ sw8(rr);
            gl2lds16(Bg + (size_t)rr*K + k0 + ch*8, &Bs[(w*(NB/4) + c*8)*64]);
        }
        __syncthreads();
        short8 af[MI][2], bfr[NJ][2];
        #pragma unroll
        for (int i = 0; i < MI; ++i) {
            af[i][0]  = ldfrag(As, wm*WROWS + i*16 + colq, quad);
            af[i][1]  = ldfrag(As, wm*WROWS + i*16 + colq, 4 + quad);
        }
        #pragma unroll
        for (int j = 0; j < NJ; ++j) {
            bfr[j][0] = ldfrag(Bs, wn*WCOLS + j*16 + colq, quad);
            bfr[j][1] = ldfrag(Bs, wn*WCOLS + j*16 + colq, 4 + quad);
        }
        #pragma unroll
        for (int i = 0; i < MI; ++i)
            #pragma unroll
            for (int j = 0; j < NJ; ++j) {
                f32x4 t = __builtin_amdgcn_mfma_f32_16x16x32_bf16(af[i][0], bfr[j][0], acc[i][j], 0, 0, 0);
                acc[i][j] = __builtin_amdgcn_mfma_f32_16x16x32_bf16(af[i][1], bfr[j][1], t, 0, 0, 0);
            }
    }
    if (EPI == 2) {
        const int b = m0 / KVN;
        const int jjbase = m0 - b*KVN;
        if (n0 < 1024) {            // K half -> knat [b*KVN + j][1024]
            bf16* kn = (bf16*)Cptr;
            #pragma unroll
            for (int j = 0; j < NJ; ++j) {
                int col = n0 + wn*WCOLS + j*16 + colq;
                #pragma unroll
                for (int i = 0; i < MI; ++i)
                    #pragma unroll
                    for (int r = 0; r < 4; ++r)
                        kn[(size_t)(b*KVN + jjbase + wm*WROWS + i*16 + quad*4 + r)*1024 + col] =
                            __float2bfloat16(acc[i][j][r]);
            }
        } else {                    // V half: LDS transpose -> coalesced stores
            // T[col_local][jj] with stride 136 shorts (272B = 16B-aligned rows,
            // bank stride 4 -> ~2-way on scalar writes). 64 cols per pass.
            unsigned short* T = Sh;      // 8704 shorts needed, 16384 available
            for (int p = 0; p < 2; ++p) {
                __syncthreads();
                if (wn == p) {
                    #pragma unroll
                    for (int j = 0; j < NJ; ++j) {
                        int cl = j*16 + colq;
                        #pragma unroll
                        for (int i = 0; i < MI; ++i)
                            #pragma unroll
                            for (int r = 0; r < 4; ++r)
                                T[cl*136 + wm*WROWS + i*16 + quad*4 + r] = f2bf_us(acc[i][j][r]);
                    }
                }
                __syncthreads();
                int hh = ((n0 + p*64) >> 6) & 15;
                unsigned short* vp = (unsigned short*)C2 + ((size_t)(b*16 + hh)*64)*KVN;
                #pragma unroll
                for (int lp = 0; lp < 4; ++lp) {
                    int idx = lp*256 + tid;
                    int cl = idx >> 4, seg = idx & 15;
                    short8 v = *(const short8*)(T + cl*136 + seg*8);
                    *(short8*)(vp + (size_t)cl*KVN + jjbase + seg*8) = v;
                }
            }
        }
    } else {
        #pragma unroll
        for (int j = 0; j < NJ; ++j) {
            int col = n0 + wn*WCOLS + j*16 + colq;
            float bj = bias ? bias[col] : 0.0f;
            #pragma unroll
            for (int i = 0; i < MI; ++i)
                #pragma unroll
                for (int r = 0; r < 4; ++r) {
                    size_t row = (size_t)(m0 + wm*WROWS + i*16 + quad*4 + r);
                    float v = acc[i][j][r] + bj;
                    if (EPI == 1) ((bf16*)Cptr)[row*N + col] = __float2bfloat16(v);
                    else          ((float*)Cptr)[row*N + col] = v;
                }
        }
    }
}

// ---------------- Flash attention: round-7 version (UNCHANGED, 216 us) ----------------
__global__ __launch_bounds__(256, 2) void attn(
    const unsigned short* __restrict__ qg,   // prescaled q bf16, [b*1024+i][1024]
    const unsigned short* __restrict__ kq,   // knat [b*KVN+j][1024]
    const unsigned short* __restrict__ vh,   // Vh [((b*16+h)*64+d)][KVN]
    const unsigned short* __restrict__ peb,  // [h][KVN][64] bf16
    bf16* __restrict__ out)                  // ao [b*1024+i][1024]
{
    __shared__ alignas(16) unsigned short Kt[2][64*64];  // 16 KB dbuf
    __shared__ alignas(16) unsigned short PEr[256*64];   // 32 KB ring
    __shared__ alignas(16) unsigned short Pb[64*64];     //  8 KB per-wave P slab

    const int tid  = threadIdx.x;
    const int lane = tid & 63, w = tid >> 6;
    const int quad = lane >> 4, colq = lane & 15;
    const int jr = lane >> 3, l7 = lane & 7;

    const int bx = blockIdx.x;
    const int b = bx & 3, h = (bx >> 2) & 15;
    const int pp = bx >> 6;                   // 0..7; bx and bx+256 share a CU
    const int qt = (pp < 4) ? pp : 11 - pp;   // pairs (p,7-p): 58 tiles per CU
    const int q0 = qt * 128;

    const unsigned short* kbase = kq  + (size_t)b*KVN*1024 + h*64;
    const unsigned short* vbase = vh  + ((size_t)((b*16 + h)*64))*KVN;
    const unsigned short* pbase = peb + (size_t)h*KVN*64;

    // Q fragments direct from global (oldest in vm queue)
    short8 qa[2][2];
    #pragma unroll
    for (int it2 = 0; it2 < 2; ++it2) {
        const unsigned short* qp = qg + ((size_t)(b*1024 + q0 + 32*w + 16*it2 + colq))*1024 + h*64;
        qa[it2][0] = ldg8(qp + quad*8);
        qa[it2][1] = ldg8(qp + 32 + quad*8);
    }
    __builtin_amdgcn_sched_barrier(0);   // pin qa loads before staging issues

    const int row0 = w*8 + jr;           // 0..31
    const int row1 = 32 + row0;          // 32..63
    const int ch0 = (l7 ^ sw8(row0))*8;
    const int ch1 = (l7 ^ sw8(row1))*8;

    auto stage_k = [&](int kv0s, int buf) {
        gl2lds16(kbase + (size_t)(kv0s + row0)*1024 + ch0, &Kt[buf][(w*8)*64]);
        gl2lds16(kbase + (size_t)(kv0s + row1)*1024 + ch1, &Kt[buf][(32 + w*8)*64]);
    };
    auto stage_pe = [&](int cbase) {     // 64 ring rows [cbase, cbase+64)
        int cg0 = cbase + row0, cg1 = cbase + row1;
        gl2lds16(pbase + (size_t)min(cg0, KVN-1)*64 + (l7 ^ sw8(cg0 & 255))*8,
                 &PEr[((cbase + w*8) & 255)*64]);
        gl2lds16(pbase + (size_t)min(cg1, KVN-1)*64 + (l7 ^ sw8(cg1 & 255))*8,
                 &PEr[((cbase + 32 + w*8) & 255)*64]);
    };

    // prologue issue order: PEfill4, PE(0)2, K(0)2, K(1)2
    const int c0p = 896 - q0;
    #pragma unroll
    for (int c = 0; c < 4; ++c) {
        int cg = c0p + c*32 + w*8 + jr;
        gl2lds16(pbase + (size_t)cg*64 + (l7 ^ sw8(cg & 255))*8,
                 &PEr[((c0p + c*32 + w*8) & 255)*64]);
    }
    stage_pe(1024 - q0);
    stage_k(0, 0);
    stage_k(64, 1);
    __builtin_amdgcn_sched_barrier(0);

    f32x4 oacc[2][4];
    float l_[2][4];
    #pragma unroll
    for (int it2 = 0; it2 < 2; ++it2) {
        #pragma unroll
        for (int dt = 0; dt < 4; ++dt) oacc[it2][dt] = (f32x4){0.f,0.f,0.f,0.f};
        #pragma unroll
        for (int r = 0; r < 4; ++r) l_[it2][r] = 0.f;
    }
    const f32x4 zero4 = (f32x4){0.f,0.f,0.f,0.f};
    const int nkv = min(36, ((q0 + 1407) >> 6) + 1);
    int cur = 0;

    for (int kvt = 0; kvt < nkv; ++kvt) {
        const int kv0 = kvt * 64;
        // V fragments direct from global, issued FIRST (youngest in vm queue;
        // consumed at PV -> latency hidden under QK/PE MFMAs + softmax)
        short8 vf[4][2];
        #pragma unroll
        for (int dt = 0; dt < 4; ++dt) {
            const unsigned short* vp = vbase + (size_t)(dt*16 + colq)*KVN + kv0;
            vf[dt][0] = ldg8(vp + quad*8);
            vf[dt][1] = ldg8(vp + 32 + quad*8);
        }
        __builtin_amdgcn_sched_barrier(0);
        // barrier A: PE(t), K(t) landed; K(t+1) (2) + vf (8) stay in flight
        if (kvt == nkv - 1) { asm volatile("s_waitcnt vmcnt(8)" ::: "memory"); }
        else                { asm volatile("s_waitcnt vmcnt(10)" ::: "memory"); }
        __builtin_amdgcn_s_barrier();

        const unsigned short* KtC = &Kt[cur][0];
        short8 kf[4][2];
        #pragma unroll
        for (int nt = 0; nt < 4; ++nt) {
            kf[nt][0] = ldfrag(KtC, nt*16 + colq, quad);
            kf[nt][1] = ldfrag(KtC, nt*16 + colq, 4 + quad);
        }
        asm volatile("s_waitcnt lgkmcnt(0)" ::: "memory");
        __builtin_amdgcn_s_barrier();        // all waves done reading Kt[cur]

        // issue next stages: PE 1 ahead, K 2 ahead (into the freed buffer)
        if (kvt + 1 < nkv) stage_pe(kv0 + 64 - q0 + 1024);
        if (kvt + 2 < nkv) stage_k(kv0 + 128, cur);
        __builtin_amdgcn_sched_barrier(0);

        // ---- MFMA phase: QK + pos band for BOTH it2 halves ----
        f32x4 facc[2][4], pacc[2][5];
        __builtin_amdgcn_s_setprio(1);
        #pragma unroll
        for (int it2 = 0; it2 < 2; ++it2)
            #pragma unroll
            for (int nt = 0; nt < 4; ++nt) {
                f32x4 t = __builtin_amdgcn_mfma_f32_16x16x32_bf16(qa[it2][0], kf[nt][0], zero4, 0, 0, 0);
                facc[it2][nt] = __builtin_amdgcn_mfma_f32_16x16x32_bf16(qa[it2][1], kf[nt][1], t, 0, 0, 0);
            }
        #pragma unroll
        for (int it2 = 0; it2 < 2; ++it2) {
            const int cb = kv0 - q0 + 1008 - 32*w - 16*it2;
            #pragma unroll
            for (int pnt = 0; pnt < 5; ++pnt) {
                int slot = (cb + pnt*16 + colq) & 255;
                short8 b0 = ldfrag(PEr, slot, quad);
                short8 b1 = ldfrag(PEr, slot, 4 + quad);
                f32x4 t = __builtin_amdgcn_mfma_f32_16x16x32_bf16(qa[it2][0], b0, zero4, 0, 0, 0);
                pacc[it2][pnt] = __builtin_amdgcn_mfma_f32_16x16x32_bf16(qa[it2][1], b1, t, 0, 0, 0);
            }
        }
        __builtin_amdgcn_s_setprio(0);

        // ---- softmax + PV per it2 (P slab reused; E1 overlaps F0) ----
        #pragma unroll
        for (int it2 = 0; it2 < 2; ++it2) {
            const int prow0 = 16*w + 4*quad;
            #pragma unroll
            for (int r = 0; r < 4; ++r) {
                int tt = colq + 15 - 4*quad - r;
                int src = (lane & 48) | (tt & 15);
                float sh[5];
                #pragma unroll
                for (int p = 0; p < 5; ++p) sh[p] = __shfl(pacc[it2][p][r], src, 64);
                int ig = q0 + 32*w + 16*it2 + 4*quad + r;
                float lsum = 0.f;
                float ps[4];
                #pragma unroll
                for (int nt = 0; nt < 4; ++nt) {
                    float g = (tt < 16) ? sh[nt] : sh[nt + 1];
                    float v = facc[it2][nt][r] + g;
                    int jg = kv0 + nt*16 + colq;
                    float s = (jg - ig > TMEM) ? -1e30f : v;
                    ps[nt] = __builtin_exp2f(s);   // log2e folded into q prescale
                    lsum += ps[nt];
                }
                l_[it2][r] += lsum;
                int prow = prow0 + r;
                int swp = sw8(prow);
                #pragma unroll
                for (int nt = 0; nt < 4; ++nt) {
                    int cc = nt*16 + colq;
                    Pb[prow*64 + (((cc >> 3) ^ swp))*8 + (cc & 7)] = f2bf_us(ps[nt]);
                }
            }
            // PV (same-wave DS ordering: own writes visible to own reads)
            short8 pa0 = ldfrag(Pb, 16*w + colq, quad);
            short8 pa1 = ldfrag(Pb, 16*w + colq, 4 + quad);
            __builtin_amdgcn_s_setprio(1);
            #pragma unroll
            for (int dt = 0; dt < 4; ++dt) {
                f32x4 t = __builtin_amdgcn_mfma_f32_16x16x32_bf16(pa0, vf[dt][0], oacc[it2][dt], 0, 0, 0);
                oacc[it2][dt] = __builtin_amdgcn_mfma_f32_16x16x32_bf16(pa1, vf[dt][1], t, 0, 0, 0);
            }
            __builtin_amdgcn_s_setprio(0);
        }
        cur ^= 1;
    }

    // ---- epilogue: reduce l across 16 colq lanes, normalize, store ----
    #pragma unroll
    for (int it2 = 0; it2 < 2; ++it2) {
        #pragma unroll
        for (int r = 0; r < 4; ++r) {
            float lt = l_[it2][r];
            #pragma unroll
            for (int off = 1; off < 16; off <<= 1) lt += __shfl_xor(lt, off, 64);
            float inv = 1.0f / lt;
            size_t row = (size_t)(b*1024 + q0 + 32*w + 16*it2 + 4*quad + r);
            #pragma unroll
            for (int dt = 0; dt < 4; ++dt)
                out[row*1024 + h*64 + dt*16 + colq] = __float2bfloat16(oacc[it2][dt][r] * inv);
        }
    }
}

// new_mem = x (fp32 bit copy, 16 MB)
__global__ __launch_bounds__(256) void copy_u4(const uint4* __restrict__ src,
                                               uint4* __restrict__ dst, int n)
{
    int i = blockIdx.x * 256 + threadIdx.x;
    if (i < n) dst[i] = src[i];
}

extern "C" void kernel_launch(void* const* d_in, const int* in_sizes, int n_in,
                              void* d_out, int out_size, void* d_ws, size_t ws_size,
                              hipStream_t stream)
{
    const float* x    = (const float*)d_in[0];
    const float* memp = (const float*)d_in[1];
    const float* cmem = (const float*)d_in[2];
    const float* pe   = (const float*)d_in[3];
    const float* Wq   = (const float*)d_in[5];
    const float* Wkv  = (const float*)d_in[6];
    const float* Wout = (const float*)d_in[7];
    const float* bout = (const float*)d_in[8];
    const float* cw   = (const float*)d_in[9];
    const float* cb   = (const float*)d_in[10];
    float* outp = (float*)d_out;

    // ws layout (bytes), total ~94.9 MB
    char* wsb = (char*)d_ws;
    unsigned short* kvin  = (unsigned short*)(wsb);              // 18,874,368
    unsigned short* knat  = (unsigned short*)(wsb + 18874368);   // 18,874,368
    unsigned short* vhb   = (unsigned short*)(wsb + 37748736);   // 18,874,368
    unsigned short* qb    = (unsigned short*)(wsb + 56623104);   //  8,388,608
    bf16*           ao    = (bf16*)(wsb + 65011712);             //  8,388,608
    unsigned short* wqb   = (unsigned short*)(wsb + 73400320);   //  2,097,152
    unsigned short* wkvb  = (unsigned short*)(wsb + 75497472);   //  4,194,304
    unsigned short* woutb = (unsigned short*)(wsb + 79691776);   //  2,097,152
    unsigned short* cw2b  = (unsigned short*)(wsb + 81788928);   //  8,388,608
    unsigned short* peb   = (unsigned short*)(wsb + 90177536);   //  4,718,592

    // stage all bf16 operands (incl. prescaled Wq with log2e, bf16 pe)
    pack<<<dim3(9856), 256, 0, stream>>>(x, memp, cmem, Wq, Wkv, Wout, cw, pe,
        kvin, wqb, wkvb, woutb, cw2b, peb);
    // q = x @ (0.125*log2e*Wq)^T  (bf16; BM=64 -> 512 blocks, 2/CU)
    gemm_mfma<1,1,64,128><<<dim3(64, 8), 256, 0, stream>>>((const bf16*)kvin, (const bf16*)wqb,
        nullptr, qb, nullptr, 4096, 1024, 1024);
    // kv = kvin @ Wkv^T -> K natural (knat), V transposed coalesced (vhb)
    gemm_mfma<2,0,128,128><<<dim3(72, 16), 256, 0, stream>>>((const bf16*)kvin, (const bf16*)wkvb,
        nullptr, knat, vhb, 9216, 2048, 1024);
    // flash attention -> ao  (512 blocks; CU-paired q-tiles)
    attn<<<dim3(512), 256, 0, stream>>>(qb, knat, vhb, peb, ao);
    // logits = ao @ Wout^T + bout -> d_out (fp32; BM=64 -> 512 blocks)
    gemm_mfma<0,0,64,128><<<dim3(64, 8), 256, 0, stream>>>(ao, (const bf16*)woutb,
        bout, outp, nullptr, 4096, 1024, 1024);
    // new_mem = x
    copy_u4<<<dim3(4096), 256, 0, stream>>>((const uint4*)x,
        (uint4*)(outp + 4194304), 1048576);
    // new_cmem = conv(mem) as GEMM (64x64 tiles -> 256 blocks)
    gemm_mfma<0,2,64,64><<<dim3(16, 16), 256, 0, stream>>>((const bf16*)kvin, (const bf16*)cw2b,
        cb, outp + 8388608, nullptr, 1024, 1024, 4096);
}